// Round 13
// baseline (238.246 us; speedup 1.0000x reference)
//
#include <hip/hip_runtime.h>
#include <math.h>

// Problem constants (hard-coded from reference)
// B=2, N=1024, C=256, HEADS=8, DH=32, INNER=256, L=3, P=9, FF=512, DEPTH=2
// LEN = 21504, level starts {0, 16384, 20480}
// GEMM A-inputs: bf16 (pre-rounded) via k_mgemm, or f32+fused-LN via k_lgemm
// (bit-identical to the old lnfused->bf16->GEMM path: same op order, same f2bf).

#define DEV __device__ __forceinline__

typedef __attribute__((ext_vector_type(8))) short bf16x8;
typedef __attribute__((ext_vector_type(4))) float floatx4;

DEV float gelu_f(float v) { return 0.5f * v * (1.0f + erff(v * 0.7071067811865475f)); }

DEV unsigned short f2bf(float f) {  // RTNE f32 -> bf16
    unsigned u = __float_as_uint(f);
    return (unsigned short)((u + 0x7fffu + ((u >> 16) & 1u)) >> 16);
}
DEV float bf2f(unsigned short s) { return __uint_as_float((unsigned)s << 16); }

// ------------------------------------------------- srcn = (src - mean) * rstd  (bf16, no gamma)
__global__ __launch_bounds__(256) void k_lnsrc(const float* __restrict__ x, unsigned short* __restrict__ out) {
    int wid = threadIdx.x >> 6, lane = threadIdx.x & 63;
    size_t row = (size_t)blockIdx.x * 4 + wid;
    float4 v = ((const float4*)(x + row * 256))[lane];
    float s = (v.x + v.y) + (v.z + v.w);
#pragma unroll
    for (int o = 32; o; o >>= 1) s += __shfl_xor(s, o);
    float mean = s * (1.0f / 256.0f);
    float dx = v.x - mean, dy = v.y - mean, dz = v.z - mean, dw = v.w - mean;
    float q = (dx * dx + dy * dy) + (dz * dz + dw * dw);
#pragma unroll
    for (int o = 32; o; o >>= 1) q += __shfl_xor(q, o);
    float rstd = 1.0f / sqrtf(q * (1.0f / 256.0f) + 1e-5f);
    ushort4 o4;
    o4.x = f2bf(dx * rstd);
    o4.y = f2bf(dy * rstd);
    o4.z = f2bf(dz * rstd);
    o4.w = f2bf(dw * rstd);
    ((ushort4*)(out + row * 256))[lane] = o4;
}

// ------------------------------------------------- row stats (mean, rstd), optional pre-add
__global__ __launch_bounds__(256) void k_rowstats(const float* __restrict__ x, const float* pre,
                                                  float* __restrict__ st) {
    int wid = threadIdx.x >> 6, lane = threadIdx.x & 63;
    size_t row = (size_t)blockIdx.x * 4 + wid;
    float4 v = ((const float4*)(x + row * 256))[lane];
    if (pre) {
        float4 p = ((const float4*)(pre + row * 256))[lane];
        v.x += p.x; v.y += p.y; v.z += p.z; v.w += p.w;
    }
    float s = (v.x + v.y) + (v.z + v.w);
#pragma unroll
    for (int o = 32; o; o >>= 1) s += __shfl_xor(s, o);
    float mean = s * (1.0f / 256.0f);
    float dx = v.x - mean, dy = v.y - mean, dz = v.z - mean, dw = v.w - mean;
    float q = (dx * dx + dy * dy) + (dz * dz + dw * dw);
#pragma unroll
    for (int o = 32; o; o >>= 1) q += __shfl_xor(q, o);
    if (lane == 0) {
        st[row * 2] = mean;
        st[row * 2 + 1] = 1.0f / sqrtf(q * (1.0f / 256.0f) + 1e-5f);
    }
}

// ---------------------------------------------------------------- cpe + parallel bval fold
__global__ __launch_bounds__(256) void k_pre(const float* __restrict__ cpos, const float* __restrict__ Wp,
                                             const float* __restrict__ bp, float* __restrict__ cpe,
                                             const float* __restrict__ ln2b, const float* __restrict__ Wval,
                                             const float* __restrict__ bval, float* __restrict__ bval2) {
    int bid = blockIdx.x, tid = threadIdx.x;
    if (bid < 2048) {
        float px = cpos[(size_t)bid * 6 + 0], py = cpos[(size_t)bid * 6 + 1];
        cpe[(size_t)bid * 256 + tid] = px * Wp[tid] + py * Wp[256 + tid] + bp[tid];
    } else {
        int idx = (bid - 2048) * 4 + (tid >> 6);  // 0..511 = d*256+n
        int d = idx >> 8, n = idx & 255;
        int lane = tid & 63;
        const float* W = Wval + (size_t)d * 65536 + n;
        const float* lb = ln2b + d * 256;
        float s = 0.0f;
#pragma unroll
        for (int kk = 0; kk < 4; kk++) {
            int k = lane + kk * 64;
            s = fmaf(lb[k], W[(size_t)k * 256], s);
        }
#pragma unroll
        for (int o = 32; o; o >>= 1) s += __shfl_xor(s, o);
        if (lane == 0) bval2[idx] = s + bval[idx];
    }
}

// ---------------------------------------------------------------- KNN (both k=16 and k=64 in one pass)
__global__ __launch_bounds__(256) void k_knn2(const float* __restrict__ pos, int* __restrict__ k16,
                                              int* __restrict__ k64) {
    __shared__ float sp[3072];
    int b = blockIdx.x >> 8;
    int n0 = (blockIdx.x & 255) * 4;
    for (int t = threadIdx.x; t < 3072; t += 256) sp[t] = pos[(size_t)b * 3072 + t];
    __syncthreads();
    int wid = threadIdx.x >> 6, lane = threadIdx.x & 63;
    int n = n0 + wid;
    float qx = sp[n * 3], qy = sp[n * 3 + 1], qz = sp[n * 3 + 2];
    float sqn = (qx * qx + qy * qy) + qz * qz;
    unsigned du[16];
#pragma unroll
    for (int t = 0; t < 16; t++) {
        int m = t * 64 + lane;
        float mx = sp[m * 3], my = sp[m * 3 + 1], mz = sp[m * 3 + 2];
        float sqm = (mx * mx + my * my) + mz * mz;
        float dt = (qx * mx + qy * my) + qz * mz;
        float d2 = (sqn + sqm) - 2.0f * dt;
        unsigned u = __float_as_uint(d2);
        du[t] = (u & 0x80000000u) ? ~u : (u | 0x80000000u);  // order-preserving
    }
    unsigned long long lmask = (1ull << lane) - 1ull;

    auto cnt_le = [&](unsigned p) {
        int c = 0;
#pragma unroll
        for (int t = 0; t < 16; t++) c += __popcll(__ballot(du[t] <= p));
        return c;
    };
    auto find_T = [&](int K) {  // smallest T with cnt_le(T) >= K (wave-uniform)
        unsigned lo = 0u, hi = 0xFFFFFFFFu;
        while (lo < hi) {
            unsigned mid = lo + ((hi - lo) >> 1);
            if (cnt_le(mid) >= K) hi = mid; else lo = mid + 1;
        }
        return hi;
    };
    auto emit = [&](int K, unsigned T, int* out) {
        int base = 0;
#pragma unroll
        for (int t = 0; t < 16; t++) {
            bool lt = du[t] < T;
            unsigned long long mk = __ballot(lt);
            if (lt) out[base + __popcll(mk & lmask)] = t * 64 + lane;
            base += __popcll(mk);
        }
        int need = K - base, eb = 0;
#pragma unroll
        for (int t = 0; t < 16; t++) {
            bool eq = du[t] == T;
            unsigned long long mk = __ballot(eq);
            if (eq) {
                int r = eb + __popcll(mk & lmask);
                if (r < need) out[base + r] = t * 64 + lane;
            }
            eb += __popcll(mk);
        }
    };
    unsigned T16 = find_T(16);
    emit(16, T16, k16 + ((size_t)b * 1024 + n) * 16);
    unsigned T64 = find_T(64);
    emit(64, T64, k64 + ((size_t)b * 1024 + n) * 64);
}

// ---------------------------------------------------------------- knn attention (bf16 in/out)
// hqkv bf16 [row][768]: q at 0, k at 256, v at 512.
template <int KK>
__global__ __launch_bounds__(256) void k_attn(const unsigned short* __restrict__ hqkv,
                                              const int* __restrict__ kidx, unsigned short* __restrict__ out) {
    int bn = blockIdx.x;
    int b = bn >> 10;
    int tid = threadIdx.x;
    __shared__ float sq[256];
    __shared__ float sa[8][KK];
    __shared__ int si[KK];
    if (tid < KK) si[tid] = kidx[(size_t)bn * KK + tid];
    sq[tid] = bf2f(hqkv[(size_t)bn * 768 + tid]) * 0.17677669529663689f;  // DH^-0.5
    __syncthreads();
    const unsigned short* kvb = hqkv + (size_t)b * 1024 * 768;
#pragma unroll
    for (int pair = tid; pair < 8 * KK; pair += 256) {
        int s = pair & (KK - 1);
        int h = pair / KK;
        const uint4* kr = (const uint4*)(kvb + (size_t)si[s] * 768 + 256 + h * 32);  // 4 x 16B = 32 bf16
        const float* q4 = &sq[h * 32];
        float a0 = 0.f, a1 = 0.f;
#pragma unroll
        for (int e = 0; e < 4; e++) {
            uint4 kv = kr[e];
            const unsigned w[4] = {kv.x, kv.y, kv.z, kv.w};
#pragma unroll
            for (int u = 0; u < 4; u++) {
                float lo = __uint_as_float(w[u] << 16);
                float hi = __uint_as_float(w[u] & 0xffff0000u);
                a0 = fmaf(lo, q4[e * 8 + u * 2], a0);
                a1 = fmaf(hi, q4[e * 8 + u * 2 + 1], a1);
            }
        }
        sa[h][s] = a0 + a1;
    }
    __syncthreads();
    int h = tid >> 5, d = tid & 31;
    float mx = -1e30f;
    for (int s = d; s < KK; s += 32) mx = fmaxf(mx, sa[h][s]);
#pragma unroll
    for (int o = 16; o; o >>= 1) mx = fmaxf(mx, __shfl_xor(mx, o, 32));
    float sum = 0.0f;
    for (int s = d; s < KK; s += 32) {
        float e = __expf(sa[h][s] - mx);
        sa[h][s] = e;
        sum += e;
    }
#pragma unroll
    for (int o = 16; o; o >>= 1) sum += __shfl_xor(sum, o, 32);
    float inv = 1.0f / sum;
    __syncthreads();
    float acc = 0.0f;
    for (int s = 0; s < KK; s++) {
        float vv = bf2f(kvb[(size_t)si[s] * 768 + 512 + tid]);
        acc += sa[h][s] * vv;
    }
    out[(size_t)bn * 256 + tid] = f2bf(acc * inv);
}

// ------------------------------------------------- ms-deform sampling
// value bf16 [b][flat][512] (both depths interleaved); value_d = depth slice. Output bf16.
__global__ __launch_bounds__(256) void k_msdeform(const float* __restrict__ offaw, const float* __restrict__ cpos,
                                                  const unsigned short* __restrict__ value_d,
                                                  unsigned short* __restrict__ out) {
    int bn = blockIdx.x;
    int b = bn >> 10;
    int tid = threadIdx.x;
    __shared__ float aw[216];
    __shared__ uint2 meta[864];  // .x = f32 weight bits, .y = row byte offset (stride 1024B)
    __shared__ float sacc[2][256];
    if (tid < 216) aw[tid] = offaw[(size_t)bn * 648 + 432 + tid];
    __syncthreads();
    if (tid < 8) {
        float mx = -1e30f;
        for (int p = 0; p < 27; p++) mx = fmaxf(mx, aw[tid * 27 + p]);
        float s = 0.0f;
        for (int p = 0; p < 27; p++) {
            float e = __expf(aw[tid * 27 + p] - mx);
            aw[tid * 27 + p] = e;
            s += e;
        }
        float inv = 1.0f / s;
        for (int p = 0; p < 27; p++) aw[tid * 27 + p] *= inv;
    }
    __syncthreads();
    if (tid < 216) {
        int h = tid / 27, lp = tid - h * 27;
        int l = lp / 9;
        const int dims[3] = {128, 64, 32};
        const int starts[3] = {0, 16384, 20480};
        int Wl = dims[l], st = starts[l];
        float rx = cpos[(size_t)bn * 6 + l * 2], ry = cpos[(size_t)bn * 6 + l * 2 + 1];
        float ox = offaw[(size_t)bn * 648 + h * 54 + lp * 2];
        float oy = offaw[(size_t)bn * 648 + h * 54 + lp * 2 + 1];
        float rw = 1.0f / (float)Wl;
        float xf = (rx + ox * rw) * (float)Wl - 0.5f;
        float yf = (ry + oy * rw) * (float)Wl - 0.5f;
        float x0 = floorf(xf), y0 = floorf(yf);
        float wgt = aw[tid];
#pragma unroll
        for (int c = 0; c < 4; c++) {
            float ix = x0 + (float)(c & 1), iy = y0 + (float)(c >> 1);
            float w = (1.0f - fabsf(xf - ix)) * (1.0f - fabsf(yf - iy));
            bool valid = (ix >= 0.0f) & (ix <= (float)(Wl - 1)) & (iy >= 0.0f) & (iy <= (float)(Wl - 1));
            uint2 m;
            if (valid && w != 0.0f) {
                m.x = __float_as_uint(w * wgt);
                m.y = (unsigned)((st + (int)iy * Wl + (int)ix) * 1024);
            } else {
                m.x = 0u;
                m.y = 0u;
            }
            meta[tid * 4 + c] = m;
        }
    }
    __syncthreads();
    int par = tid >> 7, h2 = (tid >> 4) & 7, d2 = tid & 15;
    const char* base = (const char*)(value_d + (size_t)b * 21504 * 512) + h2 * 64 + d2 * 4;
    const uint2* mp = &meta[h2 * 108 + par * 54];
    float a0 = 0.f, a1 = 0.f;
#pragma unroll
    for (int j = 0; j < 54; j++) {
        uint2 m = mp[j];
        unsigned v = *(const unsigned*)(base + m.y);
        float w = __uint_as_float(m.x);
        a0 = fmaf(w, __uint_as_float(v << 16), a0);
        a1 = fmaf(w, __uint_as_float(v & 0xffff0000u), a1);
    }
    int ch = h2 * 32 + d2 * 2;
    sacc[par][ch] = a0;
    sacc[par][ch + 1] = a1;
    __syncthreads();
    out[(size_t)bn * 256 + tid] = f2bf(sacc[0][tid] + sacc[1][tid]);
}

// ------------------------------- weight transpose+convert: Wt[n][k] = f2bf(g[k]*W[k][n])
struct TJobs {
    const float* src[18];
    const float* gam[18];
    unsigned short* dst[18];
    int K[18];
    int N[18];
};
__global__ __launch_bounds__(256) void k_tw(TJobs j) {
    int job = blockIdx.z;
    int K = j.K[job], N = j.N[job];
    int nt = (N + 31) >> 5, kt = K >> 5;
    if ((int)blockIdx.x >= nt || (int)blockIdx.y >= kt) return;
    __shared__ float t[32][33];
    const float* W = j.src[job];
    const float* g = j.gam[job];
    unsigned short* Wt = j.dst[job];
    int x = threadIdx.x & 31, y = threadIdx.x >> 5;
    int n0 = blockIdx.x << 5, k0 = blockIdx.y << 5;
#pragma unroll
    for (int i = 0; i < 32; i += 8) {
        int n = n0 + x;
        t[y + i][x] = (n < N) ? W[(size_t)(k0 + y + i) * N + n] : 0.0f;
    }
    __syncthreads();
    float gv = g ? g[k0 + x] : 1.0f;
#pragma unroll
    for (int i = 0; i < 32; i += 8) {
        int n = n0 + y + i;
        if (n < N) Wt[(size_t)n * K + k0 + x] = f2bf(gv * t[x][y + i]);
    }
}

// ---------------------------------------------------------------- bf16 MFMA GEMM (bf16 A, reg-staged)
// C = act( A[M,K](bf16) @ Wt^T + bias ) (+res). Wt[N][K] bf16.
// XOR-swizzled LDS staging; BM=64 (256 stage units) or BM=32 (128 units, guarded).
template <int BM, int BN, int WGM, int WGN, bool BIAS, bool BIAS2, bool GELUF, bool RES, bool OBF16>
__global__ __launch_bounds__(256) void k_mgemm(const unsigned short* __restrict__ A,
                                               const unsigned short* __restrict__ Bt,
                                               const float* __restrict__ bias, const float* __restrict__ bias2,
                                               int bsplit, const float* __restrict__ res, void* __restrict__ Cout,
                                               int M, int K, int Ncol) {
    constexpr int BK = 32;
    constexpr int WAVE_M = BM / WGM, WAVE_N = BN / WGN;
    constexpr int FM = WAVE_M / 16, FN = WAVE_N / 16;
    constexpr int BUN = BN / 64;
    constexpr int AUN = BM * 4;  // A 16B-units per tile
    __shared__ __align__(16) short a_lds[4][BM][8];
    __shared__ __align__(16) short b_lds[4][BN][8];
    int tid = threadIdx.x;
    int am0 = blockIdx.y * BM, bn0 = blockIdx.x * BN;
    int ar = tid >> 2, akc = tid & 3;
    const unsigned short* Arow = A + (size_t)(am0 + (ar & (BM - 1))) * K + akc * 8;
    int4 aq;
    int4 bq[BUN];
    int nsteps = K / BK;

    auto load_tile = [&](int k0) {
        if (AUN == 256 || tid < AUN) aq = *(const int4*)(Arow + k0);
#pragma unroll
        for (int jj = 0; jj < BUN; jj++) {
            int u = tid + 256 * jj;
            int col = u >> 2, kc = u & 3;
            int gn = bn0 + col;
            if (gn < Ncol)
                bq[jj] = *(const int4*)(Bt + (size_t)gn * K + k0 + kc * 8);
            else
                bq[jj] = make_int4(0, 0, 0, 0);
        }
    };
    auto write_lds = [&]() {
        if (AUN == 256 || tid < AUN) *(int4*)(&a_lds[akc][ar ^ akc][0]) = aq;
#pragma unroll
        for (int jj = 0; jj < BUN; jj++) {
            int u = tid + 256 * jj;
            int col = u >> 2, kc = u & 3;
            *(int4*)(&b_lds[kc][col ^ kc][0]) = bq[jj];
        }
    };
    int lane = tid & 63, wid = tid >> 6;
    int wm = wid / WGN, wn = wid % WGN;
    int fr = lane & 15, fkc = lane >> 4;
    floatx4 acc[FM][FN] = {};

    load_tile(0);
    for (int t = 0; t < nsteps; ++t) {
        if (t) __syncthreads();
        write_lds();
        __syncthreads();
        if (t + 1 < nsteps) load_tile((t + 1) * BK);
        bf16x8 af[FM], bf[FN];
#pragma unroll
        for (int m = 0; m < FM; m++) af[m] = *(const bf16x8*)(&a_lds[fkc][(wm * WAVE_M + m * 16 + fr) ^ fkc][0]);
#pragma unroll
        for (int n = 0; n < FN; n++) bf[n] = *(const bf16x8*)(&b_lds[fkc][(wn * WAVE_N + n * 16 + fr) ^ fkc][0]);
#pragma unroll
        for (int m = 0; m < FM; m++)
#pragma unroll
            for (int n = 0; n < FN; n++)
                acc[m][n] = __builtin_amdgcn_mfma_f32_16x16x32_bf16(af[m], bf[n], acc[m][n], 0, 0, 0);
    }
    // epilogue: C/D layout col=lane&15, row=(lane>>4)*4+reg
    int r4 = lane >> 4;
#pragma unroll
    for (int m = 0; m < FM; m++) {
        int row = am0 + wm * WAVE_M + m * 16 + r4 * 4;
#pragma unroll
        for (int n = 0; n < FN; n++) {
            int col = bn0 + wn * WAVE_N + n * 16 + fr;
            if (col < Ncol) {
                float bsc = 0.0f;
                if (BIAS) bsc = (BIAS2 && col >= bsplit) ? bias2[col - bsplit] : bias[col];
#pragma unroll
                for (int r = 0; r < 4; r++) {
                    size_t off = (size_t)(row + r) * Ncol + col;
                    float v = acc[m][n][r] + bsc;
                    if (GELUF) v = gelu_f(v);
                    if (RES) v += res[off];
                    if (OBF16)
                        ((unsigned short*)Cout)[off] = f2bf(v);
                    else
                        ((float*)Cout)[off] = v;
                }
            }
        }
    }
}

// ---------------------------------------------------------------- f32-A MFMA GEMM with fused LN staging
// A' = ((A [+pre]) - mean)*rstd*g + b  [+post], rounded to bf16 in staging --
// bit-identical to the old k_lnfused->bf16 path. BM=64, K=256 shapes only.
template <int BN, bool PRE, bool POST, bool BIAS, bool BIAS2, bool GELUF, bool OBF16>
__global__ __launch_bounds__(256) void k_lgemm(const float* __restrict__ A, const float* __restrict__ A2,
                                               const float* __restrict__ stats, const float* __restrict__ lng,
                                               const float* __restrict__ lnb,
                                               const unsigned short* __restrict__ Bt,
                                               const float* __restrict__ bias, const float* __restrict__ bias2,
                                               int bsplit, void* __restrict__ Cout, int M, int K, int Ncol) {
    constexpr int BM = 64, BK = 32;
    constexpr int WGM = 2, WGN = 2;
    constexpr int WAVE_M = BM / WGM, WAVE_N = BN / WGN;
    constexpr int FM = WAVE_M / 16, FN = WAVE_N / 16;
    constexpr int BUN = BN / 64;
    __shared__ __align__(16) short a_lds[4][BM][8];
    __shared__ __align__(16) short b_lds[4][BN][8];
    int tid = threadIdx.x;
    int am0 = blockIdx.y * BM, bn0 = blockIdx.x * BN;
    int ar = tid >> 2, akc = tid & 3;
    const float* Arow = A + (size_t)(am0 + ar) * K + akc * 8;
    const float* A2row = (PRE || POST) ? (A2 + (size_t)(am0 + ar) * 256 + akc * 8) : nullptr;
    float mean = stats[(size_t)(am0 + ar) * 2];
    float rstd = stats[(size_t)(am0 + ar) * 2 + 1];
    float4 a0, a1, p0, p1, g0, g1, c0, c1;
    int4 bq[BUN];
    int nsteps = K / BK;

    auto load_tile = [&](int k0) {
        a0 = *(const float4*)(Arow + k0);
        a1 = *(const float4*)(Arow + k0 + 4);
        if (PRE || POST) {
            p0 = *(const float4*)(A2row + k0);
            p1 = *(const float4*)(A2row + k0 + 4);
        }
        g0 = *(const float4*)(lng + k0 + akc * 8);
        g1 = *(const float4*)(lng + k0 + akc * 8 + 4);
        c0 = *(const float4*)(lnb + k0 + akc * 8);
        c1 = *(const float4*)(lnb + k0 + akc * 8 + 4);
#pragma unroll
        for (int jj = 0; jj < BUN; jj++) {
            int u = tid + 256 * jj;
            int col = u >> 2, kc = u & 3;
            int gn = bn0 + col;
            if (gn < Ncol)
                bq[jj] = *(const int4*)(Bt + (size_t)gn * K + k0 + kc * 8);
            else
                bq[jj] = make_int4(0, 0, 0, 0);
        }
    };
    auto write_lds = [&]() {
        float v[8] = {a0.x, a0.y, a0.z, a0.w, a1.x, a1.y, a1.z, a1.w};
        float pp[8] = {p0.x, p0.y, p0.z, p0.w, p1.x, p1.y, p1.z, p1.w};
        float gg[8] = {g0.x, g0.y, g0.z, g0.w, g1.x, g1.y, g1.z, g1.w};
        float bb[8] = {c0.x, c0.y, c0.z, c0.w, c1.x, c1.y, c1.z, c1.w};
        bf16x8 pk;
#pragma unroll
        for (int e = 0; e < 8; e++) {
            float t = PRE ? (v[e] + pp[e]) : v[e];
            float dx = t - mean;
            float o = dx * rstd * gg[e] + bb[e];
            if (POST) o += pp[e];
            pk[e] = (short)f2bf(o);
        }
        *(bf16x8*)(&a_lds[akc][ar ^ akc][0]) = pk;
#pragma unroll
        for (int jj = 0; jj < BUN; jj++) {
            int u = tid + 256 * jj;
            int col = u >> 2, kc = u & 3;
            *(int4*)(&b_lds[kc][col ^ kc][0]) = bq[jj];
        }
    };
    int lane = tid & 63, wid = tid >> 6;
    int wm = wid / WGN, wn = wid % WGN;
    int fr = lane & 15, fkc = lane >> 4;
    floatx4 acc[FM][FN] = {};

    load_tile(0);
    for (int t = 0; t < nsteps; ++t) {
        if (t) __syncthreads();
        write_lds();
        __syncthreads();
        if (t + 1 < nsteps) load_tile((t + 1) * BK);
        bf16x8 af[FM], bf[FN];
#pragma unroll
        for (int m = 0; m < FM; m++) af[m] = *(const bf16x8*)(&a_lds[fkc][(wm * WAVE_M + m * 16 + fr) ^ fkc][0]);
#pragma unroll
        for (int n = 0; n < FN; n++) bf[n] = *(const bf16x8*)(&b_lds[fkc][(wn * WAVE_N + n * 16 + fr) ^ fkc][0]);
#pragma unroll
        for (int m = 0; m < FM; m++)
#pragma unroll
            for (int n = 0; n < FN; n++)
                acc[m][n] = __builtin_amdgcn_mfma_f32_16x16x32_bf16(af[m], bf[n], acc[m][n], 0, 0, 0);
    }
    int r4 = lane >> 4;
#pragma unroll
    for (int m = 0; m < FM; m++) {
        int row = am0 + wm * WAVE_M + m * 16 + r4 * 4;
#pragma unroll
        for (int n = 0; n < FN; n++) {
            int col = bn0 + wn * WAVE_N + n * 16 + fr;
            if (col < Ncol) {
                float bsc = 0.0f;
                if (BIAS) bsc = (BIAS2 && col >= bsplit) ? bias2[col - bsplit] : bias[col];
#pragma unroll
                for (int r = 0; r < 4; r++) {
                    size_t off = (size_t)(row + r) * Ncol + col;
                    float v = acc[m][n][r] + bsc;
                    if (GELUF) v = gelu_f(v);
                    if (OBF16)
                        ((unsigned short*)Cout)[off] = f2bf(v);
                    else
                        ((float*)Cout)[off] = v;
                }
            }
        }
    }
}

// ================================================================ launch
extern "C" void kernel_launch(void* const* d_in, const int* in_sizes, int n_in, void* d_out, int out_size,
                              void* d_ws, size_t ws_size, hipStream_t stream) {
    const float* xin = (const float*)d_in[0];
    const float* src = (const float*)d_in[1];
    const float* cpos = (const float*)d_in[2];
    const float* pos3 = (const float*)d_in[3];
    const float* Wpos = (const float*)d_in[6];
    const float* bpos = (const float*)d_in[7];
    const float* ln1g = (const float*)d_in[8];
    const float* ln1b = (const float*)d_in[9];
    const float* ln2g = (const float*)d_in[10];
    const float* ln2b = (const float*)d_in[11];
    const float* ln3g = (const float*)d_in[12];
    const float* ln3b = (const float*)d_in[13];
    const float* Wq = (const float*)d_in[14];
    const float* Wkv = (const float*)d_in[15];
    const float* Wosa = (const float*)d_in[16];
    const float* bosa = (const float*)d_in[17];
    const float* Wval = (const float*)d_in[18];
    const float* bval = (const float*)d_in[19];
    const float* Woff = (const float*)d_in[20];
    const float* boff = (const float*)d_in[21];
    const float* Waw = (const float*)d_in[22];
    const float* baw = (const float*)d_in[23];
    const float* Woca = (const float*)d_in[24];
    const float* boca = (const float*)d_in[25];
    const float* W1 = (const float*)d_in[26];
    const float* b1f = (const float*)d_in[27];
    const float* W2 = (const float*)d_in[28];
    const float* b2f = (const float*)d_in[29];
    float* x = (float*)d_out;

    float* ws = (float*)d_ws;
    float* cpe = ws;                               // 524288
    float* offaw = cpe + 524288;                   // 1327104
    float* bval2 = offaw + 1327104;                // 512
    float* xstats = bval2 + 512;                   // 4096
    unsigned short* hqkv16 = (unsigned short*)(xstats + 4096);  // 1572864 shorts
    unsigned short* attn16 = hqkv16 + 1572864;     // 524288 shorts
    unsigned short* cab16 = attn16 + 524288;       // 524288 shorts
    unsigned short* ffmid16 = cab16 + 524288;      // 1048576 shorts
    unsigned short* srcn16 = ffmid16 + 1048576;    // 11010048 shorts
    unsigned short* value16 = srcn16 + 11010048;   // 22020096 shorts
    int* kidx16 = (int*)(value16 + 22020096);      // 32768
    int* kidx64 = kidx16 + 32768;                  // 131072
    unsigned short* wt = (unsigned short*)(kidx64 + 131072);  // 2*755712 + 131072 shorts

    const size_t WT_STRIDE = 755712;
    const size_t O_WQKV = 0, O_WOSA = 196608, O_WOFFAW = 262144, O_WOCA = 428032,
                 O_W1 = 493568, O_W2 = 624640;
    unsigned short* wtval = wt + 2 * WT_STRIDE;  // [512][256]: rows 0-255 depth0, 256-511 depth1

    TJobs tj;
    for (int d = 0; d < 2; d++) {
        unsigned short* wd = wt + (size_t)d * WT_STRIDE;
        int tb = d * 9;
        tj.src[tb + 0] = Wq + (size_t)d * 65536;    tj.gam[tb + 0] = nullptr;      tj.dst[tb + 0] = wd + O_WQKV;            tj.K[tb + 0] = 256; tj.N[tb + 0] = 256;
        tj.src[tb + 1] = Wkv + (size_t)d * 131072;  tj.gam[tb + 1] = nullptr;      tj.dst[tb + 1] = wd + O_WQKV + 65536;    tj.K[tb + 1] = 256; tj.N[tb + 1] = 512;
        tj.src[tb + 2] = Wosa + (size_t)d * 65536;  tj.gam[tb + 2] = nullptr;      tj.dst[tb + 2] = wd + O_WOSA;            tj.K[tb + 2] = 256; tj.N[tb + 2] = 256;
        tj.src[tb + 3] = Woff + (size_t)d * 110592; tj.gam[tb + 3] = nullptr;      tj.dst[tb + 3] = wd + O_WOFFAW;          tj.K[tb + 3] = 256; tj.N[tb + 3] = 432;
        tj.src[tb + 4] = Waw + (size_t)d * 55296;   tj.gam[tb + 4] = nullptr;      tj.dst[tb + 4] = wd + O_WOFFAW + 110592; tj.K[tb + 4] = 256; tj.N[tb + 4] = 216;
        tj.src[tb + 5] = Woca + (size_t)d * 65536;  tj.gam[tb + 5] = nullptr;      tj.dst[tb + 5] = wd + O_WOCA;            tj.K[tb + 5] = 256; tj.N[tb + 5] = 256;
        tj.src[tb + 6] = W1 + (size_t)d * 131072;   tj.gam[tb + 6] = nullptr;      tj.dst[tb + 6] = wd + O_W1;              tj.K[tb + 6] = 256; tj.N[tb + 6] = 512;
        tj.src[tb + 7] = W2 + (size_t)d * 131072;   tj.gam[tb + 7] = nullptr;      tj.dst[tb + 7] = wd + O_W2;              tj.K[tb + 7] = 512; tj.N[tb + 7] = 256;
        tj.src[tb + 8] = Wval + (size_t)d * 65536;  tj.gam[tb + 8] = ln2g + d * 256; tj.dst[tb + 8] = wtval + (size_t)d * 65536; tj.K[tb + 8] = 256; tj.N[tb + 8] = 256;
    }
    k_tw<<<dim3(16, 16, 18), 256, 0, stream>>>(tj);
    k_pre<<<2176, 256, 0, stream>>>(cpos, Wpos, bpos, cpe, ln2b, Wval, bval, bval2);
    k_lnsrc<<<10752, 256, 0, stream>>>(src, srcn16);
    k_knn2<<<512, 256, 0, stream>>>(pos3, kidx16, kidx64);

    // value for BOTH depths in one GEMM: srcn[43008,256](bf16) @ wtval^T -> bf16 [43008][512]
    k_mgemm<64, 256, 1, 4, true, false, false, false, true><<<dim3(2, 672), 256, 0, stream>>>(
        srcn16, wtval, bval2, nullptr, 0, nullptr, value16, 43008, 256, 512);

    for (int i = 0; i < 2; i++) {
        unsigned short* wd = wt + (size_t)i * WT_STRIDE;
        const float* xc = (i == 0) ? xin : x;
        // ---- self-attention (KNN) ----
        k_rowstats<<<512, 256, 0, stream>>>(xc, cpe, xstats);
        k_lgemm<64, true, false, false, false, false, true><<<dim3(12, 32), 256, 0, stream>>>(
            xc, cpe, xstats, ln1g + i * 256, ln1b + i * 256, wd + O_WQKV, nullptr, nullptr, 0, hqkv16, 2048, 256, 768);
        if (i == 0)
            k_attn<16><<<2048, 256, 0, stream>>>(hqkv16, kidx16, attn16);
        else
            k_attn<64><<<2048, 256, 0, stream>>>(hqkv16, kidx64, attn16);
        k_mgemm<32, 64, 2, 2, true, false, false, true, false><<<dim3(4, 64), 256, 0, stream>>>(
            attn16, wd + O_WOSA, bosa + i * 256, nullptr, 0, xc, x, 2048, 256, 256);

        // ---- ms-deform cross-attention ----
        k_rowstats<<<512, 256, 0, stream>>>(x, nullptr, xstats);
        k_lgemm<64, false, true, true, true, false, false><<<dim3(11, 32), 256, 0, stream>>>(
            x, cpe, xstats, ln2g + i * 256, ln2b + i * 256, wd + O_WOFFAW, boff + i * 432, baw + i * 216, 432,
            offaw, 2048, 256, 648);
        k_msdeform<<<2048, 256, 0, stream>>>(offaw, cpos, value16 + (size_t)i * 256, cab16);
        k_mgemm<32, 64, 2, 2, true, false, false, true, false><<<dim3(4, 64), 256, 0, stream>>>(
            cab16, wd + O_WOCA, boca + i * 256, nullptr, 0, x, x, 2048, 256, 256);

        // ---- FFN ----
        k_rowstats<<<512, 256, 0, stream>>>(x, nullptr, xstats);
        k_lgemm<64, false, false, true, false, true, true><<<dim3(8, 32), 256, 0, stream>>>(
            x, nullptr, xstats, ln3g + i * 256, ln3b + i * 256, wd + O_W1, b1f + i * 512, nullptr, 0,
            ffmid16, 2048, 256, 512);
        k_mgemm<32, 64, 2, 2, true, false, false, true, false><<<dim3(4, 64), 256, 0, stream>>>(
            ffmid16, wd + O_W2, b2f + i * 256, nullptr, 0, x, x, 2048, 512, 256);
    }
}

// Round 14
// 219.101 us; speedup vs baseline: 1.0874x; 1.0874x over previous
//
#include <hip/hip_runtime.h>
#include <math.h>

// Problem constants (hard-coded from reference)
// B=2, N=1024, C=256, HEADS=8, DH=32, INNER=256, L=3, P=9, FF=512, DEPTH=2
// LEN = 21504, level starts {0, 16384, 20480}
// All GEMM A-inputs are pre-rounded bf16 (identical numerics to in-staging f2bf).
// NOTE (r6, r13): fusing LN into GEMM A-staging regresses ~6us/site (A-path load
// inflation + register pressure). Keep LN as separate BW-trivial passes.

#define DEV __device__ __forceinline__

typedef __attribute__((ext_vector_type(8))) short bf16x8;
typedef __attribute__((ext_vector_type(4))) float floatx4;

DEV float gelu_f(float v) { return 0.5f * v * (1.0f + erff(v * 0.7071067811865475f)); }

DEV unsigned short f2bf(float f) {  // RTNE f32 -> bf16
    unsigned u = __float_as_uint(f);
    return (unsigned short)((u + 0x7fffu + ((u >> 16) & 1u)) >> 16);
}
DEV float bf2f(unsigned short s) { return __uint_as_float((unsigned)s << 16); }

// ------------------------------------------------- srcn = (src - mean) * rstd  (bf16, no gamma)
__global__ __launch_bounds__(256) void k_lnsrc(const float* __restrict__ x, unsigned short* __restrict__ out) {
    int wid = threadIdx.x >> 6, lane = threadIdx.x & 63;
    size_t row = (size_t)blockIdx.x * 4 + wid;
    float4 v = ((const float4*)(x + row * 256))[lane];
    float s = (v.x + v.y) + (v.z + v.w);
#pragma unroll
    for (int o = 32; o; o >>= 1) s += __shfl_xor(s, o);
    float mean = s * (1.0f / 256.0f);
    float dx = v.x - mean, dy = v.y - mean, dz = v.z - mean, dw = v.w - mean;
    float q = (dx * dx + dy * dy) + (dz * dz + dw * dw);
#pragma unroll
    for (int o = 32; o; o >>= 1) q += __shfl_xor(q, o);
    float rstd = 1.0f / sqrtf(q * (1.0f / 256.0f) + 1e-5f);
    ushort4 o4;
    o4.x = f2bf(dx * rstd);
    o4.y = f2bf(dy * rstd);
    o4.z = f2bf(dz * rstd);
    o4.w = f2bf(dw * rstd);
    ((ushort4*)(out + row * 256))[lane] = o4;
}

// ------------------------------------------- out(bf16) = LN(x [+pre]) * g + b [+post]
__global__ __launch_bounds__(256) void k_lnfused(const float* __restrict__ x, const float* pre, const float* post,
                                                 const float* __restrict__ g, const float* __restrict__ b,
                                                 unsigned short* __restrict__ out) {
    int wid = threadIdx.x >> 6, lane = threadIdx.x & 63;
    size_t row = (size_t)blockIdx.x * 4 + wid;
    float4 v = ((const float4*)(x + row * 256))[lane];
    if (pre) {
        float4 p = ((const float4*)(pre + row * 256))[lane];
        v.x += p.x; v.y += p.y; v.z += p.z; v.w += p.w;
    }
    float s = (v.x + v.y) + (v.z + v.w);
#pragma unroll
    for (int o = 32; o; o >>= 1) s += __shfl_xor(s, o);
    float mean = s * (1.0f / 256.0f);
    float dx = v.x - mean, dy = v.y - mean, dz = v.z - mean, dw = v.w - mean;
    float q = (dx * dx + dy * dy) + (dz * dz + dw * dw);
#pragma unroll
    for (int o = 32; o; o >>= 1) q += __shfl_xor(q, o);
    float rstd = 1.0f / sqrtf(q * (1.0f / 256.0f) + 1e-5f);
    float4 gg = ((const float4*)g)[lane], bb = ((const float4*)b)[lane];
    float4 o4;
    o4.x = dx * rstd * gg.x + bb.x;
    o4.y = dy * rstd * gg.y + bb.y;
    o4.z = dz * rstd * gg.z + bb.z;
    o4.w = dw * rstd * gg.w + bb.w;
    if (post) {
        float4 p = ((const float4*)(post + row * 256))[lane];
        o4.x += p.x; o4.y += p.y; o4.z += p.z; o4.w += p.w;
    }
    ushort4 u4;
    u4.x = f2bf(o4.x); u4.y = f2bf(o4.y); u4.z = f2bf(o4.z); u4.w = f2bf(o4.w);
    ((ushort4*)(out + row * 256))[lane] = u4;
}

// ---------------------------------------------------------------- cpe + parallel bval fold
__global__ __launch_bounds__(256) void k_pre(const float* __restrict__ cpos, const float* __restrict__ Wp,
                                             const float* __restrict__ bp, float* __restrict__ cpe,
                                             const float* __restrict__ ln2b, const float* __restrict__ Wval,
                                             const float* __restrict__ bval, float* __restrict__ bval2) {
    int bid = blockIdx.x, tid = threadIdx.x;
    if (bid < 2048) {
        float px = cpos[(size_t)bid * 6 + 0], py = cpos[(size_t)bid * 6 + 1];
        cpe[(size_t)bid * 256 + tid] = px * Wp[tid] + py * Wp[256 + tid] + bp[tid];
    } else {
        int idx = (bid - 2048) * 4 + (tid >> 6);  // 0..511 = d*256+n
        int d = idx >> 8, n = idx & 255;
        int lane = tid & 63;
        const float* W = Wval + (size_t)d * 65536 + n;
        const float* lb = ln2b + d * 256;
        float s = 0.0f;
#pragma unroll
        for (int kk = 0; kk < 4; kk++) {
            int k = lane + kk * 64;
            s = fmaf(lb[k], W[(size_t)k * 256], s);
        }
#pragma unroll
        for (int o = 32; o; o >>= 1) s += __shfl_xor(s, o);
        if (lane == 0) bval2[idx] = s + bval[idx];
    }
}

// ---------------------------------------------------------------- KNN (both k=16 and k=64 in one pass)
__global__ __launch_bounds__(256) void k_knn2(const float* __restrict__ pos, int* __restrict__ k16,
                                              int* __restrict__ k64) {
    __shared__ float sp[3072];
    int b = blockIdx.x >> 8;
    int n0 = (blockIdx.x & 255) * 4;
    for (int t = threadIdx.x; t < 3072; t += 256) sp[t] = pos[(size_t)b * 3072 + t];
    __syncthreads();
    int wid = threadIdx.x >> 6, lane = threadIdx.x & 63;
    int n = n0 + wid;
    float qx = sp[n * 3], qy = sp[n * 3 + 1], qz = sp[n * 3 + 2];
    float sqn = (qx * qx + qy * qy) + qz * qz;
    unsigned du[16];
#pragma unroll
    for (int t = 0; t < 16; t++) {
        int m = t * 64 + lane;
        float mx = sp[m * 3], my = sp[m * 3 + 1], mz = sp[m * 3 + 2];
        float sqm = (mx * mx + my * my) + mz * mz;
        float dt = (qx * mx + qy * my) + qz * mz;
        float d2 = (sqn + sqm) - 2.0f * dt;
        unsigned u = __float_as_uint(d2);
        du[t] = (u & 0x80000000u) ? ~u : (u | 0x80000000u);  // order-preserving
    }
    unsigned long long lmask = (1ull << lane) - 1ull;

    auto cnt_le = [&](unsigned p) {
        int c = 0;
#pragma unroll
        for (int t = 0; t < 16; t++) c += __popcll(__ballot(du[t] <= p));
        return c;
    };
    auto find_T = [&](int K) {  // smallest T with cnt_le(T) >= K (wave-uniform)
        unsigned lo = 0u, hi = 0xFFFFFFFFu;
        while (lo < hi) {
            unsigned mid = lo + ((hi - lo) >> 1);
            if (cnt_le(mid) >= K) hi = mid; else lo = mid + 1;
        }
        return hi;
    };
    auto emit = [&](int K, unsigned T, int* out) {
        int base = 0;
#pragma unroll
        for (int t = 0; t < 16; t++) {
            bool lt = du[t] < T;
            unsigned long long mk = __ballot(lt);
            if (lt) out[base + __popcll(mk & lmask)] = t * 64 + lane;
            base += __popcll(mk);
        }
        int need = K - base, eb = 0;
#pragma unroll
        for (int t = 0; t < 16; t++) {
            bool eq = du[t] == T;
            unsigned long long mk = __ballot(eq);
            if (eq) {
                int r = eb + __popcll(mk & lmask);
                if (r < need) out[base + r] = t * 64 + lane;
            }
            eb += __popcll(mk);
        }
    };
    unsigned T16 = find_T(16);
    emit(16, T16, k16 + ((size_t)b * 1024 + n) * 16);
    unsigned T64 = find_T(64);
    emit(64, T64, k64 + ((size_t)b * 1024 + n) * 64);
}

// ---------------------------------------------------------------- knn attention (bf16 in/out)
// hqkv bf16 [row][768]: q at 0, k at 256, v at 512.
// V-phase: 2-way s-split, dword loads (2 channels/thread), LDS reduce.
template <int KK>
__global__ __launch_bounds__(256) void k_attn(const unsigned short* __restrict__ hqkv,
                                              const int* __restrict__ kidx, unsigned short* __restrict__ out) {
    int bn = blockIdx.x;
    int b = bn >> 10;
    int tid = threadIdx.x;
    __shared__ float sq[256];
    __shared__ float sa[8][KK];
    __shared__ int si[KK];
    __shared__ float sinv[8];
    __shared__ float sacc[2][256];
    if (tid < KK) si[tid] = kidx[(size_t)bn * KK + tid];
    sq[tid] = bf2f(hqkv[(size_t)bn * 768 + tid]) * 0.17677669529663689f;  // DH^-0.5
    __syncthreads();
    const unsigned short* kvb = hqkv + (size_t)b * 1024 * 768;
#pragma unroll
    for (int pair = tid; pair < 8 * KK; pair += 256) {
        int s = pair & (KK - 1);
        int h = pair / KK;
        const uint4* kr = (const uint4*)(kvb + (size_t)si[s] * 768 + 256 + h * 32);  // 4 x 16B = 32 bf16
        const float* q4 = &sq[h * 32];
        float a0 = 0.f, a1 = 0.f;
#pragma unroll
        for (int e = 0; e < 4; e++) {
            uint4 kv = kr[e];
            const unsigned w[4] = {kv.x, kv.y, kv.z, kv.w};
#pragma unroll
            for (int u = 0; u < 4; u++) {
                float lo = __uint_as_float(w[u] << 16);
                float hi = __uint_as_float(w[u] & 0xffff0000u);
                a0 = fmaf(lo, q4[e * 8 + u * 2], a0);
                a1 = fmaf(hi, q4[e * 8 + u * 2 + 1], a1);
            }
        }
        sa[h][s] = a0 + a1;
    }
    __syncthreads();
    int h = tid >> 5, d = tid & 31;
    float mx = -1e30f;
    for (int s = d; s < KK; s += 32) mx = fmaxf(mx, sa[h][s]);
#pragma unroll
    for (int o = 16; o; o >>= 1) mx = fmaxf(mx, __shfl_xor(mx, o, 32));
    float sum = 0.0f;
    for (int s = d; s < KK; s += 32) {
        float e = __expf(sa[h][s] - mx);
        sa[h][s] = e;
        sum += e;
    }
#pragma unroll
    for (int o = 16; o; o >>= 1) sum += __shfl_xor(sum, o, 32);
    if (d == 0) sinv[h] = 1.0f / sum;
    __syncthreads();
    // V phase: par in {0,1} handles KK/2 neighbors; thread loads 2 channels (dword).
    int par = tid >> 7, rem = tid & 127;
    int h3 = rem >> 4, d3 = rem & 15;
    float b0 = 0.f, b1 = 0.f;
    int s0 = par * (KK / 2);
#pragma unroll
    for (int j = 0; j < KK / 2; j++) {
        int s = s0 + j;
        float w = sa[h3][s];
        unsigned v = *(const unsigned*)(kvb + (size_t)si[s] * 768 + 512 + h3 * 32 + d3 * 2);
        b0 = fmaf(w, __uint_as_float(v << 16), b0);
        b1 = fmaf(w, __uint_as_float(v & 0xffff0000u), b1);
    }
    int ch = h3 * 32 + d3 * 2;
    sacc[par][ch] = b0;
    sacc[par][ch + 1] = b1;
    __syncthreads();
    out[(size_t)bn * 256 + tid] = f2bf((sacc[0][tid] + sacc[1][tid]) * sinv[tid >> 5]);
}

// ------------------------------------------------- ms-deform sampling
// value bf16 [b][flat][512]; value_d = depth slice. Output bf16.
// Phase C: 4-way corner split, uint2 loads (4 channels/thread), LDS reduce.
__global__ __launch_bounds__(256) void k_msdeform(const float* __restrict__ offaw, const float* __restrict__ cpos,
                                                  const unsigned short* __restrict__ value_d,
                                                  unsigned short* __restrict__ out) {
    int bn = blockIdx.x;
    int b = bn >> 10;
    int tid = threadIdx.x;
    __shared__ float aw[216];
    __shared__ uint2 meta[864];  // .x = f32 weight bits, .y = row byte offset (stride 1024B)
    __shared__ float sacc[4][256];
    if (tid < 216) aw[tid] = offaw[(size_t)bn * 648 + 432 + tid];
    __syncthreads();
    if (tid < 8) {
        float mx = -1e30f;
        for (int p = 0; p < 27; p++) mx = fmaxf(mx, aw[tid * 27 + p]);
        float s = 0.0f;
        for (int p = 0; p < 27; p++) {
            float e = __expf(aw[tid * 27 + p] - mx);
            aw[tid * 27 + p] = e;
            s += e;
        }
        float inv = 1.0f / s;
        for (int p = 0; p < 27; p++) aw[tid * 27 + p] *= inv;
    }
    __syncthreads();
    if (tid < 216) {
        int h = tid / 27, lp = tid - h * 27;
        int l = lp / 9;
        const int dims[3] = {128, 64, 32};
        const int starts[3] = {0, 16384, 20480};
        int Wl = dims[l], st = starts[l];
        float rx = cpos[(size_t)bn * 6 + l * 2], ry = cpos[(size_t)bn * 6 + l * 2 + 1];
        float ox = offaw[(size_t)bn * 648 + h * 54 + lp * 2];
        float oy = offaw[(size_t)bn * 648 + h * 54 + lp * 2 + 1];
        float rw = 1.0f / (float)Wl;
        float xf = (rx + ox * rw) * (float)Wl - 0.5f;
        float yf = (ry + oy * rw) * (float)Wl - 0.5f;
        float x0 = floorf(xf), y0 = floorf(yf);
        float wgt = aw[tid];
#pragma unroll
        for (int c = 0; c < 4; c++) {
            float ix = x0 + (float)(c & 1), iy = y0 + (float)(c >> 1);
            float w = (1.0f - fabsf(xf - ix)) * (1.0f - fabsf(yf - iy));
            bool valid = (ix >= 0.0f) & (ix <= (float)(Wl - 1)) & (iy >= 0.0f) & (iy <= (float)(Wl - 1));
            uint2 m;
            if (valid && w != 0.0f) {
                m.x = __float_as_uint(w * wgt);
                m.y = (unsigned)((st + (int)iy * Wl + (int)ix) * 1024);
            } else {
                m.x = 0u;
                m.y = 0u;
            }
            meta[tid * 4 + c] = m;
        }
    }
    __syncthreads();
    // par (0..3) x h2 (0..7) x d2 (0..7); each thread: 27 corners x uint2 (4 bf16 channels)
    int par = tid >> 6, h2 = (tid >> 3) & 7, d2 = tid & 7;
    const char* base = (const char*)(value_d + (size_t)b * 21504 * 512) + h2 * 64 + d2 * 8;
    const uint2* mp = &meta[h2 * 108 + par * 27];
    float a0 = 0.f, a1 = 0.f, a2 = 0.f, a3 = 0.f;
#pragma unroll
    for (int j = 0; j < 27; j++) {
        uint2 m = mp[j];
        uint2 v = *(const uint2*)(base + m.y);
        float w = __uint_as_float(m.x);
        a0 = fmaf(w, __uint_as_float(v.x << 16), a0);
        a1 = fmaf(w, __uint_as_float(v.x & 0xffff0000u), a1);
        a2 = fmaf(w, __uint_as_float(v.y << 16), a2);
        a3 = fmaf(w, __uint_as_float(v.y & 0xffff0000u), a3);
    }
    int ch = h2 * 32 + d2 * 4;
    sacc[par][ch] = a0;
    sacc[par][ch + 1] = a1;
    sacc[par][ch + 2] = a2;
    sacc[par][ch + 3] = a3;
    __syncthreads();
    out[(size_t)bn * 256 + tid] = f2bf((sacc[0][tid] + sacc[1][tid]) + (sacc[2][tid] + sacc[3][tid]));
}

// ------------------------------- weight transpose+convert: Wt[n][k] = f2bf(g[k]*W[k][n])
struct TJobs {
    const float* src[18];
    const float* gam[18];
    unsigned short* dst[18];
    int K[18];
    int N[18];
};
__global__ __launch_bounds__(256) void k_tw(TJobs j) {
    int job = blockIdx.z;
    int K = j.K[job], N = j.N[job];
    int nt = (N + 31) >> 5, kt = K >> 5;
    if ((int)blockIdx.x >= nt || (int)blockIdx.y >= kt) return;
    __shared__ float t[32][33];
    const float* W = j.src[job];
    const float* g = j.gam[job];
    unsigned short* Wt = j.dst[job];
    int x = threadIdx.x & 31, y = threadIdx.x >> 5;
    int n0 = blockIdx.x << 5, k0 = blockIdx.y << 5;
#pragma unroll
    for (int i = 0; i < 32; i += 8) {
        int n = n0 + x;
        t[y + i][x] = (n < N) ? W[(size_t)(k0 + y + i) * N + n] : 0.0f;
    }
    __syncthreads();
    float gv = g ? g[k0 + x] : 1.0f;
#pragma unroll
    for (int i = 0; i < 32; i += 8) {
        int n = n0 + y + i;
        if (n < N) Wt[(size_t)n * K + k0 + x] = f2bf(gv * t[x][y + i]);
    }
}

// ---------------------------------------------------------------- bf16 MFMA GEMM (bf16 A, reg-staged)
// C = act( A[M,K](bf16) @ Wt^T + bias ) (+res). Wt[N][K] bf16.
// XOR-swizzled LDS staging; BM=64 (256 stage units) or BM=32 (128 units, guarded).
template <int BM, int BN, int WGM, int WGN, bool BIAS, bool BIAS2, bool GELUF, bool RES, bool OBF16>
__global__ __launch_bounds__(256) void k_mgemm(const unsigned short* __restrict__ A,
                                               const unsigned short* __restrict__ Bt,
                                               const float* __restrict__ bias, const float* __restrict__ bias2,
                                               int bsplit, const float* __restrict__ res, void* __restrict__ Cout,
                                               int M, int K, int Ncol) {
    constexpr int BK = 32;
    constexpr int WAVE_M = BM / WGM, WAVE_N = BN / WGN;
    constexpr int FM = WAVE_M / 16, FN = WAVE_N / 16;
    constexpr int BUN = BN / 64;
    constexpr int AUN = BM * 4;  // A 16B-units per tile
    __shared__ __align__(16) short a_lds[4][BM][8];
    __shared__ __align__(16) short b_lds[4][BN][8];
    int tid = threadIdx.x;
    int am0 = blockIdx.y * BM, bn0 = blockIdx.x * BN;
    int ar = tid >> 2, akc = tid & 3;
    const unsigned short* Arow = A + (size_t)(am0 + (ar & (BM - 1))) * K + akc * 8;
    int4 aq;
    int4 bq[BUN];
    int nsteps = K / BK;

    auto load_tile = [&](int k0) {
        if (AUN == 256 || tid < AUN) aq = *(const int4*)(Arow + k0);
#pragma unroll
        for (int jj = 0; jj < BUN; jj++) {
            int u = tid + 256 * jj;
            int col = u >> 2, kc = u & 3;
            int gn = bn0 + col;
            if (gn < Ncol)
                bq[jj] = *(const int4*)(Bt + (size_t)gn * K + k0 + kc * 8);
            else
                bq[jj] = make_int4(0, 0, 0, 0);
        }
    };
    auto write_lds = [&]() {
        if (AUN == 256 || tid < AUN) *(int4*)(&a_lds[akc][ar ^ akc][0]) = aq;
#pragma unroll
        for (int jj = 0; jj < BUN; jj++) {
            int u = tid + 256 * jj;
            int col = u >> 2, kc = u & 3;
            *(int4*)(&b_lds[kc][col ^ kc][0]) = bq[jj];
        }
    };
    int lane = tid & 63, wid = tid >> 6;
    int wm = wid / WGN, wn = wid % WGN;
    int fr = lane & 15, fkc = lane >> 4;
    floatx4 acc[FM][FN] = {};

    load_tile(0);
    for (int t = 0; t < nsteps; ++t) {
        if (t) __syncthreads();
        write_lds();
        __syncthreads();
        if (t + 1 < nsteps) load_tile((t + 1) * BK);
        bf16x8 af[FM], bf[FN];
#pragma unroll
        for (int m = 0; m < FM; m++) af[m] = *(const bf16x8*)(&a_lds[fkc][(wm * WAVE_M + m * 16 + fr) ^ fkc][0]);
#pragma unroll
        for (int n = 0; n < FN; n++) bf[n] = *(const bf16x8*)(&b_lds[fkc][(wn * WAVE_N + n * 16 + fr) ^ fkc][0]);
#pragma unroll
        for (int m = 0; m < FM; m++)
#pragma unroll
            for (int n = 0; n < FN; n++)
                acc[m][n] = __builtin_amdgcn_mfma_f32_16x16x32_bf16(af[m], bf[n], acc[m][n], 0, 0, 0);
    }
    // epilogue: C/D layout col=lane&15, row=(lane>>4)*4+reg
    int r4 = lane >> 4;
#pragma unroll
    for (int m = 0; m < FM; m++) {
        int row = am0 + wm * WAVE_M + m * 16 + r4 * 4;
#pragma unroll
        for (int n = 0; n < FN; n++) {
            int col = bn0 + wn * WAVE_N + n * 16 + fr;
            if (col < Ncol) {
                float bsc = 0.0f;
                if (BIAS) bsc = (BIAS2 && col >= bsplit) ? bias2[col - bsplit] : bias[col];
#pragma unroll
                for (int r = 0; r < 4; r++) {
                    size_t off = (size_t)(row + r) * Ncol + col;
                    float v = acc[m][n][r] + bsc;
                    if (GELUF) v = gelu_f(v);
                    if (RES) v += res[off];
                    if (OBF16)
                        ((unsigned short*)Cout)[off] = f2bf(v);
                    else
                        ((float*)Cout)[off] = v;
                }
            }
        }
    }
}

// ================================================================ launch
extern "C" void kernel_launch(void* const* d_in, const int* in_sizes, int n_in, void* d_out, int out_size,
                              void* d_ws, size_t ws_size, hipStream_t stream) {
    const float* xin = (const float*)d_in[0];
    const float* src = (const float*)d_in[1];
    const float* cpos = (const float*)d_in[2];
    const float* pos3 = (const float*)d_in[3];
    const float* Wpos = (const float*)d_in[6];
    const float* bpos = (const float*)d_in[7];
    const float* ln1g = (const float*)d_in[8];
    const float* ln1b = (const float*)d_in[9];
    const float* ln2g = (const float*)d_in[10];
    const float* ln2b = (const float*)d_in[11];
    const float* ln3g = (const float*)d_in[12];
    const float* ln3b = (const float*)d_in[13];
    const float* Wq = (const float*)d_in[14];
    const float* Wkv = (const float*)d_in[15];
    const float* Wosa = (const float*)d_in[16];
    const float* bosa = (const float*)d_in[17];
    const float* Wval = (const float*)d_in[18];
    const float* bval = (const float*)d_in[19];
    const float* Woff = (const float*)d_in[20];
    const float* boff = (const float*)d_in[21];
    const float* Waw = (const float*)d_in[22];
    const float* baw = (const float*)d_in[23];
    const float* Woca = (const float*)d_in[24];
    const float* boca = (const float*)d_in[25];
    const float* W1 = (const float*)d_in[26];
    const float* b1f = (const float*)d_in[27];
    const float* W2 = (const float*)d_in[28];
    const float* b2f = (const float*)d_in[29];
    float* x = (float*)d_out;

    float* ws = (float*)d_ws;
    float* cpe = ws;                               // 524288
    float* offaw = cpe + 524288;                   // 1327104
    float* bval2 = offaw + 1327104;                // 512
    unsigned short* hqkv16 = (unsigned short*)(bval2 + 512);   // 1572864 shorts
    unsigned short* lnout16 = hqkv16 + 1572864;    // 524288 shorts
    unsigned short* attn16 = lnout16 + 524288;     // 524288 shorts
    unsigned short* cab16 = attn16 + 524288;       // 524288 shorts
    unsigned short* ffmid16 = cab16 + 524288;      // 1048576 shorts
    unsigned short* srcn16 = ffmid16 + 1048576;    // 11010048 shorts
    unsigned short* value16 = srcn16 + 11010048;   // 22020096 shorts
    int* kidx16 = (int*)(value16 + 22020096);      // 32768
    int* kidx64 = kidx16 + 32768;                  // 131072
    unsigned short* wt = (unsigned short*)(kidx64 + 131072);  // 2*755712 + 131072 shorts

    const size_t WT_STRIDE = 755712;
    const size_t O_WQKV = 0, O_WOSA = 196608, O_WOFFAW = 262144, O_WOCA = 428032,
                 O_W1 = 493568, O_W2 = 624640;
    unsigned short* wtval = wt + 2 * WT_STRIDE;  // [512][256]: rows 0-255 depth0, 256-511 depth1

    TJobs tj;
    for (int d = 0; d < 2; d++) {
        unsigned short* wd = wt + (size_t)d * WT_STRIDE;
        int tb = d * 9;
        tj.src[tb + 0] = Wq + (size_t)d * 65536;    tj.gam[tb + 0] = nullptr;      tj.dst[tb + 0] = wd + O_WQKV;            tj.K[tb + 0] = 256; tj.N[tb + 0] = 256;
        tj.src[tb + 1] = Wkv + (size_t)d * 131072;  tj.gam[tb + 1] = nullptr;      tj.dst[tb + 1] = wd + O_WQKV + 65536;    tj.K[tb + 1] = 256; tj.N[tb + 1] = 512;
        tj.src[tb + 2] = Wosa + (size_t)d * 65536;  tj.gam[tb + 2] = nullptr;      tj.dst[tb + 2] = wd + O_WOSA;            tj.K[tb + 2] = 256; tj.N[tb + 2] = 256;
        tj.src[tb + 3] = Woff + (size_t)d * 110592; tj.gam[tb + 3] = nullptr;      tj.dst[tb + 3] = wd + O_WOFFAW;          tj.K[tb + 3] = 256; tj.N[tb + 3] = 432;
        tj.src[tb + 4] = Waw + (size_t)d * 55296;   tj.gam[tb + 4] = nullptr;      tj.dst[tb + 4] = wd + O_WOFFAW + 110592; tj.K[tb + 4] = 256; tj.N[tb + 4] = 216;
        tj.src[tb + 5] = Woca + (size_t)d * 65536;  tj.gam[tb + 5] = nullptr;      tj.dst[tb + 5] = wd + O_WOCA;            tj.K[tb + 5] = 256; tj.N[tb + 5] = 256;
        tj.src[tb + 6] = W1 + (size_t)d * 131072;   tj.gam[tb + 6] = nullptr;      tj.dst[tb + 6] = wd + O_W1;              tj.K[tb + 6] = 256; tj.N[tb + 6] = 512;
        tj.src[tb + 7] = W2 + (size_t)d * 131072;   tj.gam[tb + 7] = nullptr;      tj.dst[tb + 7] = wd + O_W2;              tj.K[tb + 7] = 512; tj.N[tb + 7] = 256;
        tj.src[tb + 8] = Wval + (size_t)d * 65536;  tj.gam[tb + 8] = ln2g + d * 256; tj.dst[tb + 8] = wtval + (size_t)d * 65536; tj.K[tb + 8] = 256; tj.N[tb + 8] = 256;
    }
    k_tw<<<dim3(16, 16, 18), 256, 0, stream>>>(tj);
    k_pre<<<2176, 256, 0, stream>>>(cpos, Wpos, bpos, cpe, ln2b, Wval, bval, bval2);
    k_lnsrc<<<10752, 256, 0, stream>>>(src, srcn16);
    k_knn2<<<512, 256, 0, stream>>>(pos3, kidx16, kidx64);

    // value for BOTH depths in one GEMM: srcn[43008,256](bf16) @ wtval^T -> bf16 [43008][512]
    k_mgemm<64, 256, 1, 4, true, false, false, false, true><<<dim3(2, 672), 256, 0, stream>>>(
        srcn16, wtval, bval2, nullptr, 0, nullptr, value16, 43008, 256, 512);

    for (int i = 0; i < 2; i++) {
        unsigned short* wd = wt + (size_t)i * WT_STRIDE;
        const float* xc = (i == 0) ? xin : x;
        // ---- self-attention (KNN) ----
        k_lnfused<<<512, 256, 0, stream>>>(xc, cpe, nullptr, ln1g + i * 256, ln1b + i * 256, lnout16);
        k_mgemm<64, 64, 2, 2, false, false, false, false, true><<<dim3(12, 32), 256, 0, stream>>>(
            lnout16, wd + O_WQKV, nullptr, nullptr, 0, nullptr, hqkv16, 2048, 256, 768);
        if (i == 0)
            k_attn<16><<<2048, 256, 0, stream>>>(hqkv16, kidx16, attn16);
        else
            k_attn<64><<<2048, 256, 0, stream>>>(hqkv16, kidx64, attn16);
        k_mgemm<32, 64, 2, 2, true, false, false, true, false><<<dim3(4, 64), 256, 0, stream>>>(
            attn16, wd + O_WOSA, bosa + i * 256, nullptr, 0, xc, x, 2048, 256, 256);

        // ---- ms-deform cross-attention ----
        k_lnfused<<<512, 256, 0, stream>>>(x, nullptr, cpe, ln2g + i * 256, ln2b + i * 256, lnout16);
        k_mgemm<64, 64, 2, 2, true, true, false, false, false><<<dim3(11, 32), 256, 0, stream>>>(
            lnout16, wd + O_WOFFAW, boff + i * 432, baw + i * 216, 432, nullptr, offaw, 2048, 256, 648);
        k_msdeform<<<2048, 256, 0, stream>>>(offaw, cpos, value16 + (size_t)i * 256, cab16);
        k_mgemm<32, 64, 2, 2, true, false, false, true, false><<<dim3(4, 64), 256, 0, stream>>>(
            cab16, wd + O_WOCA, boca + i * 256, nullptr, 0, x, x, 2048, 256, 256);

        // ---- FFN ----
        k_lnfused<<<512, 256, 0, stream>>>(x, nullptr, nullptr, ln3g + i * 256, ln3b + i * 256, lnout16);
        k_mgemm<64, 64, 2, 2, true, false, true, false, true><<<dim3(8, 32), 256, 0, stream>>>(
            lnout16, wd + O_W1, b1f + i * 512, nullptr, 0, nullptr, ffmid16, 2048, 256, 512);
        k_mgemm<32, 64, 2, 2, true, false, false, true, false><<<dim3(4, 64), 256, 0, stream>>>(
            ffmid16, wd + O_W2, b2f + i * 256, nullptr, 0, x, x, 2048, 512, 256);
    }
}

// Round 15
// 212.502 us; speedup vs baseline: 1.1211x; 1.0311x over previous
//
#include <hip/hip_runtime.h>
#include <math.h>

// Problem constants (hard-coded from reference)
// B=2, N=1024, C=256, HEADS=8, DH=32, INNER=256, L=3, P=9, FF=512, DEPTH=2
// LEN = 21504, level starts {0, 16384, 20480}
// All GEMM A-inputs are pre-rounded bf16 (identical numerics to in-staging f2bf).
// NOTES: (r6,r13) LN-in-GEMM staging regresses ~6us/site -- keep LN separate.
//        (r8,r9) occupancy > intra-wave pipelining for these small GEMMs.
//        (r10) never merge high-VGPR kernels (knn) into shared dispatch (spill).
//        (r14) gather kernels are latency-bound, not load-issue-bound.

#define DEV __device__ __forceinline__

typedef __attribute__((ext_vector_type(8))) short bf16x8;
typedef __attribute__((ext_vector_type(4))) float floatx4;

DEV float gelu_f(float v) { return 0.5f * v * (1.0f + erff(v * 0.7071067811865475f)); }

DEV unsigned short f2bf(float f) {  // RTNE f32 -> bf16
    unsigned u = __float_as_uint(f);
    return (unsigned short)((u + 0x7fffu + ((u >> 16) & 1u)) >> 16);
}
DEV float bf2f(unsigned short s) { return __uint_as_float((unsigned)s << 16); }

// ------------------------------------------- out(bf16) = LN(x [+pre]) * g + b [+post]
__global__ __launch_bounds__(256) void k_lnfused(const float* __restrict__ x, const float* pre, const float* post,
                                                 const float* __restrict__ g, const float* __restrict__ b,
                                                 unsigned short* __restrict__ out) {
    int wid = threadIdx.x >> 6, lane = threadIdx.x & 63;
    size_t row = (size_t)blockIdx.x * 4 + wid;
    float4 v = ((const float4*)(x + row * 256))[lane];
    if (pre) {
        float4 p = ((const float4*)(pre + row * 256))[lane];
        v.x += p.x; v.y += p.y; v.z += p.z; v.w += p.w;
    }
    float s = (v.x + v.y) + (v.z + v.w);
#pragma unroll
    for (int o = 32; o; o >>= 1) s += __shfl_xor(s, o);
    float mean = s * (1.0f / 256.0f);
    float dx = v.x - mean, dy = v.y - mean, dz = v.z - mean, dw = v.w - mean;
    float q = (dx * dx + dy * dy) + (dz * dz + dw * dw);
#pragma unroll
    for (int o = 32; o; o >>= 1) q += __shfl_xor(q, o);
    float rstd = 1.0f / sqrtf(q * (1.0f / 256.0f) + 1e-5f);
    float4 gg = ((const float4*)g)[lane], bb = ((const float4*)b)[lane];
    float4 o4;
    o4.x = dx * rstd * gg.x + bb.x;
    o4.y = dy * rstd * gg.y + bb.y;
    o4.z = dz * rstd * gg.z + bb.z;
    o4.w = dw * rstd * gg.w + bb.w;
    if (post) {
        float4 p = ((const float4*)(post + row * 256))[lane];
        o4.x += p.x; o4.y += p.y; o4.z += p.z; o4.w += p.w;
    }
    ushort4 u4;
    u4.x = f2bf(o4.x); u4.y = f2bf(o4.y); u4.z = f2bf(o4.z); u4.w = f2bf(o4.w);
    ((ushort4*)(out + row * 256))[lane] = u4;
}

// ---------------------------------------------------------------- merged prologue (low-VGPR branches only)
// blocks [0,4608): weight transpose; [4608,6784): cpe + parallel bval fold;
// [6784,17536): lnsrc. (KNN stays standalone: 40+ VGPR, would spill here -- r10.)
struct TJobs {
    const float* src[18];
    const float* gam[18];
    unsigned short* dst[18];
    int K[18];
    int N[18];
};
__global__ __launch_bounds__(256) void k_init(TJobs j, const float* __restrict__ cpos,
                                              const float* __restrict__ Wp, const float* __restrict__ bp,
                                              float* __restrict__ cpe, const float* __restrict__ ln2b,
                                              const float* __restrict__ Wval, const float* __restrict__ bval,
                                              float* __restrict__ bval2, const float* __restrict__ srcf,
                                              unsigned short* __restrict__ srcn) {
    __shared__ float t[32][33];
    int bid = blockIdx.x, tid = threadIdx.x;
    if (bid < 4608) {
        // ---- weight transpose+convert: Wt[n][k] = f2bf(g[k]*W[k][n]) ----
        int job = bid >> 8, sub = bid & 255;
        int bx = sub & 15, by = sub >> 4;
        int K = j.K[job], N = j.N[job];
        int nt = (N + 31) >> 5, kt = K >> 5;
        if (bx >= nt || by >= kt) return;
        const float* W = j.src[job];
        const float* g = j.gam[job];
        unsigned short* Wt = j.dst[job];
        int x = tid & 31, y = tid >> 5;
        int n0 = bx << 5, k0 = by << 5;
#pragma unroll
        for (int i = 0; i < 32; i += 8) {
            int n = n0 + x;
            t[y + i][x] = (n < N) ? W[(size_t)(k0 + y + i) * N + n] : 0.0f;
        }
        __syncthreads();
        float gv = g ? g[k0 + x] : 1.0f;
#pragma unroll
        for (int i = 0; i < 32; i += 8) {
            int n = n0 + y + i;
            if (n < N) Wt[(size_t)n * K + k0 + x] = f2bf(gv * t[x][y + i]);
        }
    } else if (bid < 6784) {
        int bb = bid - 4608;
        if (bb < 2048) {
            float px = cpos[(size_t)bb * 6 + 0], py = cpos[(size_t)bb * 6 + 1];
            cpe[(size_t)bb * 256 + tid] = px * Wp[tid] + py * Wp[256 + tid] + bp[tid];
        } else {
            int idx = (bb - 2048) * 4 + (tid >> 6);  // 0..511 = d*256+n
            int d = idx >> 8, n = idx & 255;
            int lane = tid & 63;
            const float* W = Wval + (size_t)d * 65536 + n;
            const float* lb = ln2b + d * 256;
            float s = 0.0f;
#pragma unroll
            for (int kk = 0; kk < 4; kk++) {
                int k = lane + kk * 64;
                s = fmaf(lb[k], W[(size_t)k * 256], s);
            }
#pragma unroll
            for (int o = 32; o; o >>= 1) s += __shfl_xor(s, o);
            if (lane == 0) bval2[idx] = s + bval[idx];
        }
    } else {
        // ---- srcn = (src - mean) * rstd (bf16, no gamma) ----
        int wid = tid >> 6, lane = tid & 63;
        size_t row = (size_t)(bid - 6784) * 4 + wid;
        float4 v = ((const float4*)(srcf + row * 256))[lane];
        float s = (v.x + v.y) + (v.z + v.w);
#pragma unroll
        for (int o = 32; o; o >>= 1) s += __shfl_xor(s, o);
        float mean = s * (1.0f / 256.0f);
        float dx = v.x - mean, dy = v.y - mean, dz = v.z - mean, dw = v.w - mean;
        float q = (dx * dx + dy * dy) + (dz * dz + dw * dw);
#pragma unroll
        for (int o = 32; o; o >>= 1) q += __shfl_xor(q, o);
        float rstd = 1.0f / sqrtf(q * (1.0f / 256.0f) + 1e-5f);
        ushort4 o4;
        o4.x = f2bf(dx * rstd);
        o4.y = f2bf(dy * rstd);
        o4.z = f2bf(dz * rstd);
        o4.w = f2bf(dw * rstd);
        ((ushort4*)(srcn + row * 256))[lane] = o4;
    }
}

// ---------------------------------------------------------------- KNN (both k=16 and k=64 in one pass)
__global__ __launch_bounds__(256) void k_knn2(const float* __restrict__ pos, int* __restrict__ k16,
                                              int* __restrict__ k64) {
    __shared__ float sp[3072];
    int b = blockIdx.x >> 8;
    int n0 = (blockIdx.x & 255) * 4;
    for (int t = threadIdx.x; t < 3072; t += 256) sp[t] = pos[(size_t)b * 3072 + t];
    __syncthreads();
    int wid = threadIdx.x >> 6, lane = threadIdx.x & 63;
    int n = n0 + wid;
    float qx = sp[n * 3], qy = sp[n * 3 + 1], qz = sp[n * 3 + 2];
    float sqn = (qx * qx + qy * qy) + qz * qz;
    unsigned du[16];
#pragma unroll
    for (int t = 0; t < 16; t++) {
        int m = t * 64 + lane;
        float mx = sp[m * 3], my = sp[m * 3 + 1], mz = sp[m * 3 + 2];
        float sqm = (mx * mx + my * my) + mz * mz;
        float dt = (qx * mx + qy * my) + qz * mz;
        float d2 = (sqn + sqm) - 2.0f * dt;
        unsigned u = __float_as_uint(d2);
        du[t] = (u & 0x80000000u) ? ~u : (u | 0x80000000u);  // order-preserving
    }
    unsigned long long lmask = (1ull << lane) - 1ull;

    auto cnt_le = [&](unsigned p) {
        int c = 0;
#pragma unroll
        for (int t = 0; t < 16; t++) c += __popcll(__ballot(du[t] <= p));
        return c;
    };
    auto find_T = [&](int K) {  // smallest T with cnt_le(T) >= K (wave-uniform)
        unsigned lo = 0u, hi = 0xFFFFFFFFu;
        while (lo < hi) {
            unsigned mid = lo + ((hi - lo) >> 1);
            if (cnt_le(mid) >= K) hi = mid; else lo = mid + 1;
        }
        return hi;
    };
    auto emit = [&](int K, unsigned T, int* out) {
        int base = 0;
#pragma unroll
        for (int t = 0; t < 16; t++) {
            bool lt = du[t] < T;
            unsigned long long mk = __ballot(lt);
            if (lt) out[base + __popcll(mk & lmask)] = t * 64 + lane;
            base += __popcll(mk);
        }
        int need = K - base, eb = 0;
#pragma unroll
        for (int t = 0; t < 16; t++) {
            bool eq = du[t] == T;
            unsigned long long mk = __ballot(eq);
            if (eq) {
                int r = eb + __popcll(mk & lmask);
                if (r < need) out[base + r] = t * 64 + lane;
            }
            eb += __popcll(mk);
        }
    };
    unsigned T16 = find_T(16);
    emit(16, T16, k16 + ((size_t)b * 1024 + n) * 16);
    unsigned T64 = find_T(64);
    emit(64, T64, k64 + ((size_t)b * 1024 + n) * 64);
}

// ---------------------------------------------------------------- knn attention (bf16 in/out)
// hqkv bf16 [row][768]: q at 0, k at 256, v at 512.
template <int KK>
__global__ __launch_bounds__(256) void k_attn(const unsigned short* __restrict__ hqkv,
                                              const int* __restrict__ kidx, unsigned short* __restrict__ out) {
    int bn = blockIdx.x;
    int b = bn >> 10;
    int tid = threadIdx.x;
    __shared__ float sq[256];
    __shared__ float sa[8][KK];
    __shared__ int si[KK];
    __shared__ float sinv[8];
    __shared__ float sacc[2][256];
    if (tid < KK) si[tid] = kidx[(size_t)bn * KK + tid];
    sq[tid] = bf2f(hqkv[(size_t)bn * 768 + tid]) * 0.17677669529663689f;  // DH^-0.5
    __syncthreads();
    const unsigned short* kvb = hqkv + (size_t)b * 1024 * 768;
#pragma unroll
    for (int pair = tid; pair < 8 * KK; pair += 256) {
        int s = pair & (KK - 1);
        int h = pair / KK;
        const uint4* kr = (const uint4*)(kvb + (size_t)si[s] * 768 + 256 + h * 32);  // 4 x 16B = 32 bf16
        const float* q4 = &sq[h * 32];
        float a0 = 0.f, a1 = 0.f;
#pragma unroll
        for (int e = 0; e < 4; e++) {
            uint4 kv = kr[e];
            const unsigned w[4] = {kv.x, kv.y, kv.z, kv.w};
#pragma unroll
            for (int u = 0; u < 4; u++) {
                float lo = __uint_as_float(w[u] << 16);
                float hi = __uint_as_float(w[u] & 0xffff0000u);
                a0 = fmaf(lo, q4[e * 8 + u * 2], a0);
                a1 = fmaf(hi, q4[e * 8 + u * 2 + 1], a1);
            }
        }
        sa[h][s] = a0 + a1;
    }
    __syncthreads();
    int h = tid >> 5, d = tid & 31;
    float mx = -1e30f;
    for (int s = d; s < KK; s += 32) mx = fmaxf(mx, sa[h][s]);
#pragma unroll
    for (int o = 16; o; o >>= 1) mx = fmaxf(mx, __shfl_xor(mx, o, 32));
    float sum = 0.0f;
    for (int s = d; s < KK; s += 32) {
        float e = __expf(sa[h][s] - mx);
        sa[h][s] = e;
        sum += e;
    }
#pragma unroll
    for (int o = 16; o; o >>= 1) sum += __shfl_xor(sum, o, 32);
    if (d == 0) sinv[h] = 1.0f / sum;
    __syncthreads();
    // V phase: par in {0,1} handles KK/2 neighbors; thread loads 2 channels (dword).
    int par = tid >> 7, rem = tid & 127;
    int h3 = rem >> 4, d3 = rem & 15;
    float b0 = 0.f, b1 = 0.f;
    int s0 = par * (KK / 2);
#pragma unroll
    for (int j = 0; j < KK / 2; j++) {
        int s = s0 + j;
        float w = sa[h3][s];
        unsigned v = *(const unsigned*)(kvb + (size_t)si[s] * 768 + 512 + h3 * 32 + d3 * 2);
        b0 = fmaf(w, __uint_as_float(v << 16), b0);
        b1 = fmaf(w, __uint_as_float(v & 0xffff0000u), b1);
    }
    int ch = h3 * 32 + d3 * 2;
    sacc[par][ch] = b0;
    sacc[par][ch + 1] = b1;
    __syncthreads();
    out[(size_t)bn * 256 + tid] = f2bf((sacc[0][tid] + sacc[1][tid]) * sinv[tid >> 5]);
}

// ------------------------------------------------- ms-deform sampling
// value bf16 [b][flat][512]; value_d = depth slice. Output bf16.
__global__ __launch_bounds__(256) void k_msdeform(const float* __restrict__ offaw, const float* __restrict__ cpos,
                                                  const unsigned short* __restrict__ value_d,
                                                  unsigned short* __restrict__ out) {
    int bn = blockIdx.x;
    int b = bn >> 10;
    int tid = threadIdx.x;
    __shared__ float aw[216];
    __shared__ uint2 meta[864];  // .x = f32 weight bits, .y = row byte offset (stride 1024B)
    __shared__ float sacc[4][256];
    if (tid < 216) aw[tid] = offaw[(size_t)bn * 648 + 432 + tid];
    __syncthreads();
    if (tid < 8) {
        float mx = -1e30f;
        for (int p = 0; p < 27; p++) mx = fmaxf(mx, aw[tid * 27 + p]);
        float s = 0.0f;
        for (int p = 0; p < 27; p++) {
            float e = __expf(aw[tid * 27 + p] - mx);
            aw[tid * 27 + p] = e;
            s += e;
        }
        float inv = 1.0f / s;
        for (int p = 0; p < 27; p++) aw[tid * 27 + p] *= inv;
    }
    __syncthreads();
    if (tid < 216) {
        int h = tid / 27, lp = tid - h * 27;
        int l = lp / 9;
        const int dims[3] = {128, 64, 32};
        const int starts[3] = {0, 16384, 20480};
        int Wl = dims[l], st = starts[l];
        float rx = cpos[(size_t)bn * 6 + l * 2], ry = cpos[(size_t)bn * 6 + l * 2 + 1];
        float ox = offaw[(size_t)bn * 648 + h * 54 + lp * 2];
        float oy = offaw[(size_t)bn * 648 + h * 54 + lp * 2 + 1];
        float rw = 1.0f / (float)Wl;
        float xf = (rx + ox * rw) * (float)Wl - 0.5f;
        float yf = (ry + oy * rw) * (float)Wl - 0.5f;
        float x0 = floorf(xf), y0 = floorf(yf);
        float wgt = aw[tid];
#pragma unroll
        for (int c = 0; c < 4; c++) {
            float ix = x0 + (float)(c & 1), iy = y0 + (float)(c >> 1);
            float w = (1.0f - fabsf(xf - ix)) * (1.0f - fabsf(yf - iy));
            bool valid = (ix >= 0.0f) & (ix <= (float)(Wl - 1)) & (iy >= 0.0f) & (iy <= (float)(Wl - 1));
            uint2 m;
            if (valid && w != 0.0f) {
                m.x = __float_as_uint(w * wgt);
                m.y = (unsigned)((st + (int)iy * Wl + (int)ix) * 1024);
            } else {
                m.x = 0u;
                m.y = 0u;
            }
            meta[tid * 4 + c] = m;
        }
    }
    __syncthreads();
    // par (0..3) x h2 (0..7) x d2 (0..7); each thread: 27 corners x uint2 (4 bf16 channels)
    int par = tid >> 6, h2 = (tid >> 3) & 7, d2 = tid & 7;
    const char* base = (const char*)(value_d + (size_t)b * 21504 * 512) + h2 * 64 + d2 * 8;
    const uint2* mp = &meta[h2 * 108 + par * 27];
    float a0 = 0.f, a1 = 0.f, a2 = 0.f, a3 = 0.f;
#pragma unroll
    for (int j = 0; j < 27; j++) {
        uint2 m = mp[j];
        uint2 v = *(const uint2*)(base + m.y);
        float w = __uint_as_float(m.x);
        a0 = fmaf(w, __uint_as_float(v.x << 16), a0);
        a1 = fmaf(w, __uint_as_float(v.x & 0xffff0000u), a1);
        a2 = fmaf(w, __uint_as_float(v.y << 16), a2);
        a3 = fmaf(w, __uint_as_float(v.y & 0xffff0000u), a3);
    }
    int ch = h2 * 32 + d2 * 4;
    sacc[par][ch] = a0;
    sacc[par][ch + 1] = a1;
    sacc[par][ch + 2] = a2;
    sacc[par][ch + 3] = a3;
    __syncthreads();
    out[(size_t)bn * 256 + tid] = f2bf((sacc[0][tid] + sacc[1][tid]) + (sacc[2][tid] + sacc[3][tid]));
}

// ---------------------------------------------------------------- bf16 MFMA GEMM (bf16 A, reg-staged)
// C = act( A[M,K](bf16) @ Wt^T + bias ) (+res). Wt[N][K] bf16.
// XOR-swizzled LDS staging; BM=64 (256 stage units) or BM=32 (128 units, guarded).
template <int BM, int BN, int WGM, int WGN, bool BIAS, bool BIAS2, bool GELUF, bool RES, bool OBF16>
__global__ __launch_bounds__(256) void k_mgemm(const unsigned short* __restrict__ A,
                                               const unsigned short* __restrict__ Bt,
                                               const float* __restrict__ bias, const float* __restrict__ bias2,
                                               int bsplit, const float* __restrict__ res, void* __restrict__ Cout,
                                               int M, int K, int Ncol) {
    constexpr int BK = 32;
    constexpr int WAVE_M = BM / WGM, WAVE_N = BN / WGN;
    constexpr int FM = WAVE_M / 16, FN = WAVE_N / 16;
    constexpr int BUN = BN / 64;
    constexpr int AUN = BM * 4;  // A 16B-units per tile
    __shared__ __align__(16) short a_lds[4][BM][8];
    __shared__ __align__(16) short b_lds[4][BN][8];
    int tid = threadIdx.x;
    int am0 = blockIdx.y * BM, bn0 = blockIdx.x * BN;
    int ar = tid >> 2, akc = tid & 3;
    const unsigned short* Arow = A + (size_t)(am0 + (ar & (BM - 1))) * K + akc * 8;
    int4 aq;
    int4 bq[BUN];
    int nsteps = K / BK;

    auto load_tile = [&](int k0) {
        if (AUN == 256 || tid < AUN) aq = *(const int4*)(Arow + k0);
#pragma unroll
        for (int jj = 0; jj < BUN; jj++) {
            int u = tid + 256 * jj;
            int col = u >> 2, kc = u & 3;
            int gn = bn0 + col;
            if (gn < Ncol)
                bq[jj] = *(const int4*)(Bt + (size_t)gn * K + k0 + kc * 8);
            else
                bq[jj] = make_int4(0, 0, 0, 0);
        }
    };
    auto write_lds = [&]() {
        if (AUN == 256 || tid < AUN) *(int4*)(&a_lds[akc][ar ^ akc][0]) = aq;
#pragma unroll
        for (int jj = 0; jj < BUN; jj++) {
            int u = tid + 256 * jj;
            int col = u >> 2, kc = u & 3;
            *(int4*)(&b_lds[kc][col ^ kc][0]) = bq[jj];
        }
    };
    int lane = tid & 63, wid = tid >> 6;
    int wm = wid / WGN, wn = wid % WGN;
    int fr = lane & 15, fkc = lane >> 4;
    floatx4 acc[FM][FN] = {};

    load_tile(0);
    for (int t = 0; t < nsteps; ++t) {
        if (t) __syncthreads();
        write_lds();
        __syncthreads();
        if (t + 1 < nsteps) load_tile((t + 1) * BK);
        bf16x8 af[FM], bf[FN];
#pragma unroll
        for (int m = 0; m < FM; m++) af[m] = *(const bf16x8*)(&a_lds[fkc][(wm * WAVE_M + m * 16 + fr) ^ fkc][0]);
#pragma unroll
        for (int n = 0; n < FN; n++) bf[n] = *(const bf16x8*)(&b_lds[fkc][(wn * WAVE_N + n * 16 + fr) ^ fkc][0]);
#pragma unroll
        for (int m = 0; m < FM; m++)
#pragma unroll
            for (int n = 0; n < FN; n++)
                acc[m][n] = __builtin_amdgcn_mfma_f32_16x16x32_bf16(af[m], bf[n], acc[m][n], 0, 0, 0);
    }
    // epilogue: C/D layout col=lane&15, row=(lane>>4)*4+reg
    int r4 = lane >> 4;
#pragma unroll
    for (int m = 0; m < FM; m++) {
        int row = am0 + wm * WAVE_M + m * 16 + r4 * 4;
#pragma unroll
        for (int n = 0; n < FN; n++) {
            int col = bn0 + wn * WAVE_N + n * 16 + fr;
            if (col < Ncol) {
                float bsc = 0.0f;
                if (BIAS) bsc = (BIAS2 && col >= bsplit) ? bias2[col - bsplit] : bias[col];
#pragma unroll
                for (int r = 0; r < 4; r++) {
                    size_t off = (size_t)(row + r) * Ncol + col;
                    float v = acc[m][n][r] + bsc;
                    if (GELUF) v = gelu_f(v);
                    if (RES) v += res[off];
                    if (OBF16)
                        ((unsigned short*)Cout)[off] = f2bf(v);
                    else
                        ((float*)Cout)[off] = v;
                }
            }
        }
    }
}

// ================================================================ launch
extern "C" void kernel_launch(void* const* d_in, const int* in_sizes, int n_in, void* d_out, int out_size,
                              void* d_ws, size_t ws_size, hipStream_t stream) {
    const float* xin = (const float*)d_in[0];
    const float* src = (const float*)d_in[1];
    const float* cpos = (const float*)d_in[2];
    const float* pos3 = (const float*)d_in[3];
    const float* Wpos = (const float*)d_in[6];
    const float* bpos = (const float*)d_in[7];
    const float* ln1g = (const float*)d_in[8];
    const float* ln1b = (const float*)d_in[9];
    const float* ln2g = (const float*)d_in[10];
    const float* ln2b = (const float*)d_in[11];
    const float* ln3g = (const float*)d_in[12];
    const float* ln3b = (const float*)d_in[13];
    const float* Wq = (const float*)d_in[14];
    const float* Wkv = (const float*)d_in[15];
    const float* Wosa = (const float*)d_in[16];
    const float* bosa = (const float*)d_in[17];
    const float* Wval = (const float*)d_in[18];
    const float* bval = (const float*)d_in[19];
    const float* Woff = (const float*)d_in[20];
    const float* boff = (const float*)d_in[21];
    const float* Waw = (const float*)d_in[22];
    const float* baw = (const float*)d_in[23];
    const float* Woca = (const float*)d_in[24];
    const float* boca = (const float*)d_in[25];
    const float* W1 = (const float*)d_in[26];
    const float* b1f = (const float*)d_in[27];
    const float* W2 = (const float*)d_in[28];
    const float* b2f = (const float*)d_in[29];
    float* x = (float*)d_out;

    float* ws = (float*)d_ws;
    float* cpe = ws;                               // 524288
    float* offaw = cpe + 524288;                   // 1327104
    float* bval2 = offaw + 1327104;                // 512
    unsigned short* hqkv16 = (unsigned short*)(bval2 + 512);   // 1572864 shorts
    unsigned short* lnout16 = hqkv16 + 1572864;    // 524288 shorts
    unsigned short* attn16 = lnout16 + 524288;     // 524288 shorts
    unsigned short* cab16 = attn16 + 524288;       // 524288 shorts
    unsigned short* ffmid16 = cab16 + 524288;      // 1048576 shorts
    unsigned short* srcn16 = ffmid16 + 1048576;    // 11010048 shorts
    unsigned short* value16 = srcn16 + 11010048;   // 22020096 shorts
    int* kidx16 = (int*)(value16 + 22020096);      // 32768
    int* kidx64 = kidx16 + 32768;                  // 131072
    unsigned short* wt = (unsigned short*)(kidx64 + 131072);  // 2*755712 + 131072 shorts

    const size_t WT_STRIDE = 755712;
    const size_t O_WQKV = 0, O_WOSA = 196608, O_WOFFAW = 262144, O_WOCA = 428032,
                 O_W1 = 493568, O_W2 = 624640;
    unsigned short* wtval = wt + 2 * WT_STRIDE;  // [512][256]: rows 0-255 depth0, 256-511 depth1

    TJobs tj;
    for (int d = 0; d < 2; d++) {
        unsigned short* wd = wt + (size_t)d * WT_STRIDE;
        int tb = d * 9;
        tj.src[tb + 0] = Wq + (size_t)d * 65536;    tj.gam[tb + 0] = nullptr;      tj.dst[tb + 0] = wd + O_WQKV;            tj.K[tb + 0] = 256; tj.N[tb + 0] = 256;
        tj.src[tb + 1] = Wkv + (size_t)d * 131072;  tj.gam[tb + 1] = nullptr;      tj.dst[tb + 1] = wd + O_WQKV + 65536;    tj.K[tb + 1] = 256; tj.N[tb + 1] = 512;
        tj.src[tb + 2] = Wosa + (size_t)d * 65536;  tj.gam[tb + 2] = nullptr;      tj.dst[tb + 2] = wd + O_WOSA;            tj.K[tb + 2] = 256; tj.N[tb + 2] = 256;
        tj.src[tb + 3] = Woff + (size_t)d * 110592; tj.gam[tb + 3] = nullptr;      tj.dst[tb + 3] = wd + O_WOFFAW;          tj.K[tb + 3] = 256; tj.N[tb + 3] = 432;
        tj.src[tb + 4] = Waw + (size_t)d * 55296;   tj.gam[tb + 4] = nullptr;      tj.dst[tb + 4] = wd + O_WOFFAW + 110592; tj.K[tb + 4] = 256; tj.N[tb + 4] = 216;
        tj.src[tb + 5] = Woca + (size_t)d * 65536;  tj.gam[tb + 5] = nullptr;      tj.dst[tb + 5] = wd + O_WOCA;            tj.K[tb + 5] = 256; tj.N[tb + 5] = 256;
        tj.src[tb + 6] = W1 + (size_t)d * 131072;   tj.gam[tb + 6] = nullptr;      tj.dst[tb + 6] = wd + O_W1;              tj.K[tb + 6] = 256; tj.N[tb + 6] = 512;
        tj.src[tb + 7] = W2 + (size_t)d * 131072;   tj.gam[tb + 7] = nullptr;      tj.dst[tb + 7] = wd + O_W2;              tj.K[tb + 7] = 512; tj.N[tb + 7] = 256;
        tj.src[tb + 8] = Wval + (size_t)d * 65536;  tj.gam[tb + 8] = ln2g + d * 256; tj.dst[tb + 8] = wtval + (size_t)d * 65536; tj.K[tb + 8] = 256; tj.N[tb + 8] = 256;
    }
    // merged prologue: tw(4608) + cpe/fold(2176) + lnsrc(10752) = 17536 blocks
    k_init<<<17536, 256, 0, stream>>>(tj, cpos, Wpos, bpos, cpe, ln2b, Wval, bval, bval2, src, srcn16);
    k_knn2<<<512, 256, 0, stream>>>(pos3, kidx16, kidx64);

    // value for BOTH depths in one GEMM: srcn[43008,256](bf16) @ wtval^T -> bf16 [43008][512]
    k_mgemm<64, 256, 1, 4, true, false, false, false, true><<<dim3(2, 672), 256, 0, stream>>>(
        srcn16, wtval, bval2, nullptr, 0, nullptr, value16, 43008, 256, 512);

    for (int i = 0; i < 2; i++) {
        unsigned short* wd = wt + (size_t)i * WT_STRIDE;
        const float* xc = (i == 0) ? xin : x;
        // ---- self-attention (KNN) ----
        k_lnfused<<<512, 256, 0, stream>>>(xc, cpe, nullptr, ln1g + i * 256, ln1b + i * 256, lnout16);
        k_mgemm<64, 64, 2, 2, false, false, false, false, true><<<dim3(12, 32), 256, 0, stream>>>(
            lnout16, wd + O_WQKV, nullptr, nullptr, 0, nullptr, hqkv16, 2048, 256, 768);
        if (i == 0)
            k_attn<16><<<2048, 256, 0, stream>>>(hqkv16, kidx16, attn16);
        else
            k_attn<64><<<2048, 256, 0, stream>>>(hqkv16, kidx64, attn16);
        k_mgemm<32, 64, 2, 2, true, false, false, true, false><<<dim3(4, 64), 256, 0, stream>>>(
            attn16, wd + O_WOSA, bosa + i * 256, nullptr, 0, xc, x, 2048, 256, 256);

        // ---- ms-deform cross-attention ----
        k_lnfused<<<512, 256, 0, stream>>>(x, nullptr, cpe, ln2g + i * 256, ln2b + i * 256, lnout16);
        k_mgemm<64, 64, 2, 2, true, true, false, false, false><<<dim3(11, 32), 256, 0, stream>>>(
            lnout16, wd + O_WOFFAW, boff + i * 432, baw + i * 216, 432, nullptr, offaw, 2048, 256, 648);
        k_msdeform<<<2048, 256, 0, stream>>>(offaw, cpos, value16 + (size_t)i * 256, cab16);
        k_mgemm<32, 64, 2, 2, true, false, false, true, false><<<dim3(4, 64), 256, 0, stream>>>(
            cab16, wd + O_WOCA, boca + i * 256, nullptr, 0, x, x, 2048, 256, 256);

        // ---- FFN ----
        k_lnfused<<<512, 256, 0, stream>>>(x, nullptr, nullptr, ln3g + i * 256, ln3b + i * 256, lnout16);
        k_mgemm<64, 64, 2, 2, true, false, true, false, true><<<dim3(8, 32), 256, 0, stream>>>(
            lnout16, wd + O_W1, b1f + i * 512, nullptr, 0, nullptr, ffmid16, 2048, 256, 512);
        k_mgemm<32, 64, 2, 2, true, false, false, true, false><<<dim3(4, 64), 256, 0, stream>>>(
            ffmid16, wd + O_W2, b2f + i * 256, nullptr, 0, x, x, 2048, 512, 256);
    }
}

// Round 16
// 212.240 us; speedup vs baseline: 1.1225x; 1.0012x over previous
//
#include <hip/hip_runtime.h>
#include <math.h>

// Problem constants (hard-coded from reference)
// B=2, N=1024, C=256, HEADS=8, DH=32, INNER=256, L=3, P=9, FF=512, DEPTH=2
// LEN = 21504, level starts {0, 16384, 20480}
// All GEMM A-inputs are pre-rounded bf16 (identical numerics to in-staging f2bf).
// NOTES: (r6,r13) LN-in-GEMM staging regresses ~6us/site -- keep LN separate.
//        (r8,r9) occupancy > intra-wave pipelining for these small GEMMs.
//        (r10) never merge high-VGPR kernels (knn) into shared dispatch (spill).
//        (r14) gather kernels are latency-bound, not load-issue-bound.

#define DEV __device__ __forceinline__

typedef __attribute__((ext_vector_type(8))) short bf16x8;
typedef __attribute__((ext_vector_type(4))) float floatx4;

DEV float gelu_f(float v) { return 0.5f * v * (1.0f + erff(v * 0.7071067811865475f)); }

DEV unsigned short f2bf(float f) {  // RTNE f32 -> bf16
    unsigned u = __float_as_uint(f);
    return (unsigned short)((u + 0x7fffu + ((u >> 16) & 1u)) >> 16);
}
DEV float bf2f(unsigned short s) { return __uint_as_float((unsigned)s << 16); }

// ------------------------------------------- out(bf16) = LN(x [+pre]) * g + b [+post]
__global__ __launch_bounds__(256) void k_lnfused(const float* __restrict__ x, const float* pre, const float* post,
                                                 const float* __restrict__ g, const float* __restrict__ b,
                                                 unsigned short* __restrict__ out) {
    int wid = threadIdx.x >> 6, lane = threadIdx.x & 63;
    size_t row = (size_t)blockIdx.x * 4 + wid;
    float4 v = ((const float4*)(x + row * 256))[lane];
    if (pre) {
        float4 p = ((const float4*)(pre + row * 256))[lane];
        v.x += p.x; v.y += p.y; v.z += p.z; v.w += p.w;
    }
    float s = (v.x + v.y) + (v.z + v.w);
#pragma unroll
    for (int o = 32; o; o >>= 1) s += __shfl_xor(s, o);
    float mean = s * (1.0f / 256.0f);
    float dx = v.x - mean, dy = v.y - mean, dz = v.z - mean, dw = v.w - mean;
    float q = (dx * dx + dy * dy) + (dz * dz + dw * dw);
#pragma unroll
    for (int o = 32; o; o >>= 1) q += __shfl_xor(q, o);
    float rstd = 1.0f / sqrtf(q * (1.0f / 256.0f) + 1e-5f);
    float4 gg = ((const float4*)g)[lane], bb = ((const float4*)b)[lane];
    float4 o4;
    o4.x = dx * rstd * gg.x + bb.x;
    o4.y = dy * rstd * gg.y + bb.y;
    o4.z = dz * rstd * gg.z + bb.z;
    o4.w = dw * rstd * gg.w + bb.w;
    if (post) {
        float4 p = ((const float4*)(post + row * 256))[lane];
        o4.x += p.x; o4.y += p.y; o4.z += p.z; o4.w += p.w;
    }
    ushort4 u4;
    u4.x = f2bf(o4.x); u4.y = f2bf(o4.y); u4.z = f2bf(o4.z); u4.w = f2bf(o4.w);
    ((ushort4*)(out + row * 256))[lane] = u4;
}

// ---------------------------------------------------------------- merged prologue (low-VGPR branches only)
// blocks [0,4608): weight transpose; [4608,6784): cpe + parallel bval fold;
// [6784,17536): lnsrc. (KNN stays standalone: 40+ VGPR, would spill here -- r10.)
struct TJobs {
    const float* src[18];
    const float* gam[18];
    unsigned short* dst[18];
    int K[18];
    int N[18];
};
__global__ __launch_bounds__(256) void k_init(TJobs j, const float* __restrict__ cpos,
                                              const float* __restrict__ Wp, const float* __restrict__ bp,
                                              float* __restrict__ cpe, const float* __restrict__ ln2b,
                                              const float* __restrict__ Wval, const float* __restrict__ bval,
                                              float* __restrict__ bval2, const float* __restrict__ srcf,
                                              unsigned short* __restrict__ srcn) {
    __shared__ float t[32][33];
    int bid = blockIdx.x, tid = threadIdx.x;
    if (bid < 4608) {
        // ---- weight transpose+convert: Wt[n][k] = f2bf(g[k]*W[k][n]) ----
        int job = bid >> 8, sub = bid & 255;
        int bx = sub & 15, by = sub >> 4;
        int K = j.K[job], N = j.N[job];
        int nt = (N + 31) >> 5, kt = K >> 5;
        if (bx >= nt || by >= kt) return;
        const float* W = j.src[job];
        const float* g = j.gam[job];
        unsigned short* Wt = j.dst[job];
        int x = tid & 31, y = tid >> 5;
        int n0 = bx << 5, k0 = by << 5;
#pragma unroll
        for (int i = 0; i < 32; i += 8) {
            int n = n0 + x;
            t[y + i][x] = (n < N) ? W[(size_t)(k0 + y + i) * N + n] : 0.0f;
        }
        __syncthreads();
        float gv = g ? g[k0 + x] : 1.0f;
#pragma unroll
        for (int i = 0; i < 32; i += 8) {
            int n = n0 + y + i;
            if (n < N) Wt[(size_t)n * K + k0 + x] = f2bf(gv * t[x][y + i]);
        }
    } else if (bid < 6784) {
        int bb = bid - 4608;
        if (bb < 2048) {
            float px = cpos[(size_t)bb * 6 + 0], py = cpos[(size_t)bb * 6 + 1];
            cpe[(size_t)bb * 256 + tid] = px * Wp[tid] + py * Wp[256 + tid] + bp[tid];
        } else {
            int idx = (bb - 2048) * 4 + (tid >> 6);  // 0..511 = d*256+n
            int d = idx >> 8, n = idx & 255;
            int lane = tid & 63;
            const float* W = Wval + (size_t)d * 65536 + n;
            const float* lb = ln2b + d * 256;
            float s = 0.0f;
#pragma unroll
            for (int kk = 0; kk < 4; kk++) {
                int k = lane + kk * 64;
                s = fmaf(lb[k], W[(size_t)k * 256], s);
            }
#pragma unroll
            for (int o = 32; o; o >>= 1) s += __shfl_xor(s, o);
            if (lane == 0) bval2[idx] = s + bval[idx];
        }
    } else {
        // ---- srcn = (src - mean) * rstd (bf16, no gamma) ----
        int wid = tid >> 6, lane = tid & 63;
        size_t row = (size_t)(bid - 6784) * 4 + wid;
        float4 v = ((const float4*)(srcf + row * 256))[lane];
        float s = (v.x + v.y) + (v.z + v.w);
#pragma unroll
        for (int o = 32; o; o >>= 1) s += __shfl_xor(s, o);
        float mean = s * (1.0f / 256.0f);
        float dx = v.x - mean, dy = v.y - mean, dz = v.z - mean, dw = v.w - mean;
        float q = (dx * dx + dy * dy) + (dz * dz + dw * dw);
#pragma unroll
        for (int o = 32; o; o >>= 1) q += __shfl_xor(q, o);
        float rstd = 1.0f / sqrtf(q * (1.0f / 256.0f) + 1e-5f);
        ushort4 o4;
        o4.x = f2bf(dx * rstd);
        o4.y = f2bf(dy * rstd);
        o4.z = f2bf(dz * rstd);
        o4.w = f2bf(dw * rstd);
        ((ushort4*)(srcn + row * 256))[lane] = o4;
    }
}

// ---------------------------------------------------------------- KNN (both k=16 and k=64 in one pass)
__global__ __launch_bounds__(256) void k_knn2(const float* __restrict__ pos, int* __restrict__ k16,
                                              int* __restrict__ k64) {
    __shared__ float sp[3072];
    int b = blockIdx.x >> 8;
    int n0 = (blockIdx.x & 255) * 4;
    for (int t = threadIdx.x; t < 3072; t += 256) sp[t] = pos[(size_t)b * 3072 + t];
    __syncthreads();
    int wid = threadIdx.x >> 6, lane = threadIdx.x & 63;
    int n = n0 + wid;
    float qx = sp[n * 3], qy = sp[n * 3 + 1], qz = sp[n * 3 + 2];
    float sqn = (qx * qx + qy * qy) + qz * qz;
    unsigned du[16];
#pragma unroll
    for (int t = 0; t < 16; t++) {
        int m = t * 64 + lane;
        float mx = sp[m * 3], my = sp[m * 3 + 1], mz = sp[m * 3 + 2];
        float sqm = (mx * mx + my * my) + mz * mz;
        float dt = (qx * mx + qy * my) + qz * mz;
        float d2 = (sqn + sqm) - 2.0f * dt;
        unsigned u = __float_as_uint(d2);
        du[t] = (u & 0x80000000u) ? ~u : (u | 0x80000000u);  // order-preserving
    }
    unsigned long long lmask = (1ull << lane) - 1ull;

    auto cnt_le = [&](unsigned p) {
        int c = 0;
#pragma unroll
        for (int t = 0; t < 16; t++) c += __popcll(__ballot(du[t] <= p));
        return c;
    };
    auto find_T = [&](int K) {  // smallest T with cnt_le(T) >= K (wave-uniform)
        unsigned lo = 0u, hi = 0xFFFFFFFFu;
        while (lo < hi) {
            unsigned mid = lo + ((hi - lo) >> 1);
            if (cnt_le(mid) >= K) hi = mid; else lo = mid + 1;
        }
        return hi;
    };
    auto emit = [&](int K, unsigned T, int* out) {
        int base = 0;
#pragma unroll
        for (int t = 0; t < 16; t++) {
            bool lt = du[t] < T;
            unsigned long long mk = __ballot(lt);
            if (lt) out[base + __popcll(mk & lmask)] = t * 64 + lane;
            base += __popcll(mk);
        }
        int need = K - base, eb = 0;
#pragma unroll
        for (int t = 0; t < 16; t++) {
            bool eq = du[t] == T;
            unsigned long long mk = __ballot(eq);
            if (eq) {
                int r = eb + __popcll(mk & lmask);
                if (r < need) out[base + r] = t * 64 + lane;
            }
            eb += __popcll(mk);
        }
    };
    unsigned T16 = find_T(16);
    emit(16, T16, k16 + ((size_t)b * 1024 + n) * 16);
    unsigned T64 = find_T(64);
    emit(64, T64, k64 + ((size_t)b * 1024 + n) * 64);
}

// ---------------------------------------------------------------- knn attention (bf16 in/out)
// hqkv bf16 [row][768]: q at 0, k at 256, v at 512.
template <int KK>
__global__ __launch_bounds__(256) void k_attn(const unsigned short* __restrict__ hqkv,
                                              const int* __restrict__ kidx, unsigned short* __restrict__ out) {
    int bn = blockIdx.x;
    int b = bn >> 10;
    int tid = threadIdx.x;
    __shared__ float sq[256];
    __shared__ float sa[8][KK];
    __shared__ int si[KK];
    __shared__ float sinv[8];
    __shared__ float sacc[2][256];
    if (tid < KK) si[tid] = kidx[(size_t)bn * KK + tid];
    sq[tid] = bf2f(hqkv[(size_t)bn * 768 + tid]) * 0.17677669529663689f;  // DH^-0.5
    __syncthreads();
    const unsigned short* kvb = hqkv + (size_t)b * 1024 * 768;
#pragma unroll
    for (int pair = tid; pair < 8 * KK; pair += 256) {
        int s = pair & (KK - 1);
        int h = pair / KK;
        const uint4* kr = (const uint4*)(kvb + (size_t)si[s] * 768 + 256 + h * 32);  // 4 x 16B = 32 bf16
        const float* q4 = &sq[h * 32];
        float a0 = 0.f, a1 = 0.f;
#pragma unroll
        for (int e = 0; e < 4; e++) {
            uint4 kv = kr[e];
            const unsigned w[4] = {kv.x, kv.y, kv.z, kv.w};
#pragma unroll
            for (int u = 0; u < 4; u++) {
                float lo = __uint_as_float(w[u] << 16);
                float hi = __uint_as_float(w[u] & 0xffff0000u);
                a0 = fmaf(lo, q4[e * 8 + u * 2], a0);
                a1 = fmaf(hi, q4[e * 8 + u * 2 + 1], a1);
            }
        }
        sa[h][s] = a0 + a1;
    }
    __syncthreads();
    int h = tid >> 5, d = tid & 31;
    float mx = -1e30f;
    for (int s = d; s < KK; s += 32) mx = fmaxf(mx, sa[h][s]);
#pragma unroll
    for (int o = 16; o; o >>= 1) mx = fmaxf(mx, __shfl_xor(mx, o, 32));
    float sum = 0.0f;
    for (int s = d; s < KK; s += 32) {
        float e = __expf(sa[h][s] - mx);
        sa[h][s] = e;
        sum += e;
    }
#pragma unroll
    for (int o = 16; o; o >>= 1) sum += __shfl_xor(sum, o, 32);
    if (d == 0) sinv[h] = 1.0f / sum;
    __syncthreads();
    // V phase: par in {0,1} handles KK/2 neighbors; thread loads 2 channels (dword).
    int par = tid >> 7, rem = tid & 127;
    int h3 = rem >> 4, d3 = rem & 15;
    float b0 = 0.f, b1 = 0.f;
    int s0 = par * (KK / 2);
#pragma unroll
    for (int j = 0; j < KK / 2; j++) {
        int s = s0 + j;
        float w = sa[h3][s];
        unsigned v = *(const unsigned*)(kvb + (size_t)si[s] * 768 + 512 + h3 * 32 + d3 * 2);
        b0 = fmaf(w, __uint_as_float(v << 16), b0);
        b1 = fmaf(w, __uint_as_float(v & 0xffff0000u), b1);
    }
    int ch = h3 * 32 + d3 * 2;
    sacc[par][ch] = b0;
    sacc[par][ch + 1] = b1;
    __syncthreads();
    out[(size_t)bn * 256 + tid] = f2bf((sacc[0][tid] + sacc[1][tid]) * sinv[tid >> 5]);
}

// ------------------------------------------------- ms-deform sampling
// value bf16 [b][flat][512]; value_d = depth slice. Output bf16.
// Softmax: wave-parallel (8 x 32-lane groups, one head each).
__global__ __launch_bounds__(256) void k_msdeform(const float* __restrict__ offaw, const float* __restrict__ cpos,
                                                  const unsigned short* __restrict__ value_d,
                                                  unsigned short* __restrict__ out) {
    int bn = blockIdx.x;
    int b = bn >> 10;
    int tid = threadIdx.x;
    __shared__ float aw[216];
    __shared__ uint2 meta[864];  // .x = f32 weight bits, .y = row byte offset (stride 1024B)
    __shared__ float sacc[4][256];
    if (tid < 216) aw[tid] = offaw[(size_t)bn * 648 + 432 + tid];
    __syncthreads();
    {  // wave-parallel per-head softmax over 27: group g (32 lanes) = head g
        int g = tid >> 5, l = tid & 31;
        float v = (l < 27) ? aw[g * 27 + l] : -1e30f;
        float mx = v;
#pragma unroll
        for (int o = 16; o; o >>= 1) mx = fmaxf(mx, __shfl_xor(mx, o, 32));
        float e = (l < 27) ? __expf(v - mx) : 0.0f;
        float s = e;
#pragma unroll
        for (int o = 16; o; o >>= 1) s += __shfl_xor(s, o, 32);
        float inv = 1.0f / s;
        if (l < 27) aw[g * 27 + l] = e * inv;
    }
    __syncthreads();
    if (tid < 216) {
        int h = tid / 27, lp = tid - h * 27;
        int l = lp / 9;
        const int dims[3] = {128, 64, 32};
        const int starts[3] = {0, 16384, 20480};
        int Wl = dims[l], st = starts[l];
        float rx = cpos[(size_t)bn * 6 + l * 2], ry = cpos[(size_t)bn * 6 + l * 2 + 1];
        float ox = offaw[(size_t)bn * 648 + h * 54 + lp * 2];
        float oy = offaw[(size_t)bn * 648 + h * 54 + lp * 2 + 1];
        float rw = 1.0f / (float)Wl;
        float xf = (rx + ox * rw) * (float)Wl - 0.5f;
        float yf = (ry + oy * rw) * (float)Wl - 0.5f;
        float x0 = floorf(xf), y0 = floorf(yf);
        float wgt = aw[tid];
#pragma unroll
        for (int c = 0; c < 4; c++) {
            float ix = x0 + (float)(c & 1), iy = y0 + (float)(c >> 1);
            float w = (1.0f - fabsf(xf - ix)) * (1.0f - fabsf(yf - iy));
            bool valid = (ix >= 0.0f) & (ix <= (float)(Wl - 1)) & (iy >= 0.0f) & (iy <= (float)(Wl - 1));
            uint2 m;
            if (valid && w != 0.0f) {
                m.x = __float_as_uint(w * wgt);
                m.y = (unsigned)((st + (int)iy * Wl + (int)ix) * 1024);
            } else {
                m.x = 0u;
                m.y = 0u;
            }
            meta[tid * 4 + c] = m;
        }
    }
    __syncthreads();
    // par (0..3) x h2 (0..7) x d2 (0..7); each thread: 27 corners x uint2 (4 bf16 channels)
    int par = tid >> 6, h2 = (tid >> 3) & 7, d2 = tid & 7;
    const char* base = (const char*)(value_d + (size_t)b * 21504 * 512) + h2 * 64 + d2 * 8;
    const uint2* mp = &meta[h2 * 108 + par * 27];
    float a0 = 0.f, a1 = 0.f, a2 = 0.f, a3 = 0.f;
#pragma unroll
    for (int j = 0; j < 27; j++) {
        uint2 m = mp[j];
        uint2 v = *(const uint2*)(base + m.y);
        float w = __uint_as_float(m.x);
        a0 = fmaf(w, __uint_as_float(v.x << 16), a0);
        a1 = fmaf(w, __uint_as_float(v.x & 0xffff0000u), a1);
        a2 = fmaf(w, __uint_as_float(v.y << 16), a2);
        a3 = fmaf(w, __uint_as_float(v.y & 0xffff0000u), a3);
    }
    int ch = h2 * 32 + d2 * 4;
    sacc[par][ch] = a0;
    sacc[par][ch + 1] = a1;
    sacc[par][ch + 2] = a2;
    sacc[par][ch + 3] = a3;
    __syncthreads();
    out[(size_t)bn * 256 + tid] = f2bf((sacc[0][tid] + sacc[1][tid]) + (sacc[2][tid] + sacc[3][tid]));
}

// ---------------------------------------------------------------- bf16 MFMA GEMM (bf16 A, reg-staged)
// C = act( A[M,K](bf16) @ Wt^T + bias ) (+res). Wt[N][K] bf16.
// XOR-swizzled LDS staging; BM=64 (256 stage units) or BM=32 (128 units, guarded).
template <int BM, int BN, int WGM, int WGN, bool BIAS, bool BIAS2, bool GELUF, bool RES, bool OBF16>
__global__ __launch_bounds__(256) void k_mgemm(const unsigned short* __restrict__ A,
                                               const unsigned short* __restrict__ Bt,
                                               const float* __restrict__ bias, const float* __restrict__ bias2,
                                               int bsplit, const float* __restrict__ res, void* __restrict__ Cout,
                                               int M, int K, int Ncol) {
    constexpr int BK = 32;
    constexpr int WAVE_M = BM / WGM, WAVE_N = BN / WGN;
    constexpr int FM = WAVE_M / 16, FN = WAVE_N / 16;
    constexpr int BUN = BN / 64;
    constexpr int AUN = BM * 4;  // A 16B-units per tile
    __shared__ __align__(16) short a_lds[4][BM][8];
    __shared__ __align__(16) short b_lds[4][BN][8];
    int tid = threadIdx.x;
    int am0 = blockIdx.y * BM, bn0 = blockIdx.x * BN;
    int ar = tid >> 2, akc = tid & 3;
    const unsigned short* Arow = A + (size_t)(am0 + (ar & (BM - 1))) * K + akc * 8;
    int4 aq;
    int4 bq[BUN];
    int nsteps = K / BK;

    auto load_tile = [&](int k0) {
        if (AUN == 256 || tid < AUN) aq = *(const int4*)(Arow + k0);
#pragma unroll
        for (int jj = 0; jj < BUN; jj++) {
            int u = tid + 256 * jj;
            int col = u >> 2, kc = u & 3;
            int gn = bn0 + col;
            if (gn < Ncol)
                bq[jj] = *(const int4*)(Bt + (size_t)gn * K + k0 + kc * 8);
            else
                bq[jj] = make_int4(0, 0, 0, 0);
        }
    };
    auto write_lds = [&]() {
        if (AUN == 256 || tid < AUN) *(int4*)(&a_lds[akc][ar ^ akc][0]) = aq;
#pragma unroll
        for (int jj = 0; jj < BUN; jj++) {
            int u = tid + 256 * jj;
            int col = u >> 2, kc = u & 3;
            *(int4*)(&b_lds[kc][col ^ kc][0]) = bq[jj];
        }
    };
    int lane = tid & 63, wid = tid >> 6;
    int wm = wid / WGN, wn = wid % WGN;
    int fr = lane & 15, fkc = lane >> 4;
    floatx4 acc[FM][FN] = {};

    load_tile(0);
    for (int t = 0; t < nsteps; ++t) {
        if (t) __syncthreads();
        write_lds();
        __syncthreads();
        if (t + 1 < nsteps) load_tile((t + 1) * BK);
        bf16x8 af[FM], bf[FN];
#pragma unroll
        for (int m = 0; m < FM; m++) af[m] = *(const bf16x8*)(&a_lds[fkc][(wm * WAVE_M + m * 16 + fr) ^ fkc][0]);
#pragma unroll
        for (int n = 0; n < FN; n++) bf[n] = *(const bf16x8*)(&b_lds[fkc][(wn * WAVE_N + n * 16 + fr) ^ fkc][0]);
#pragma unroll
        for (int m = 0; m < FM; m++)
#pragma unroll
            for (int n = 0; n < FN; n++)
                acc[m][n] = __builtin_amdgcn_mfma_f32_16x16x32_bf16(af[m], bf[n], acc[m][n], 0, 0, 0);
    }
    // epilogue: C/D layout col=lane&15, row=(lane>>4)*4+reg
    int r4 = lane >> 4;
#pragma unroll
    for (int m = 0; m < FM; m++) {
        int row = am0 + wm * WAVE_M + m * 16 + r4 * 4;
#pragma unroll
        for (int n = 0; n < FN; n++) {
            int col = bn0 + wn * WAVE_N + n * 16 + fr;
            if (col < Ncol) {
                float bsc = 0.0f;
                if (BIAS) bsc = (BIAS2 && col >= bsplit) ? bias2[col - bsplit] : bias[col];
#pragma unroll
                for (int r = 0; r < 4; r++) {
                    size_t off = (size_t)(row + r) * Ncol + col;
                    float v = acc[m][n][r] + bsc;
                    if (GELUF) v = gelu_f(v);
                    if (RES) v += res[off];
                    if (OBF16)
                        ((unsigned short*)Cout)[off] = f2bf(v);
                    else
                        ((float*)Cout)[off] = v;
                }
            }
        }
    }
}

// ================================================================ launch
extern "C" void kernel_launch(void* const* d_in, const int* in_sizes, int n_in, void* d_out, int out_size,
                              void* d_ws, size_t ws_size, hipStream_t stream) {
    const float* xin = (const float*)d_in[0];
    const float* src = (const float*)d_in[1];
    const float* cpos = (const float*)d_in[2];
    const float* pos3 = (const float*)d_in[3];
    const float* Wpos = (const float*)d_in[6];
    const float* bpos = (const float*)d_in[7];
    const float* ln1g = (const float*)d_in[8];
    const float* ln1b = (const float*)d_in[9];
    const float* ln2g = (const float*)d_in[10];
    const float* ln2b = (const float*)d_in[11];
    const float* ln3g = (const float*)d_in[12];
    const float* ln3b = (const float*)d_in[13];
    const float* Wq = (const float*)d_in[14];
    const float* Wkv = (const float*)d_in[15];
    const float* Wosa = (const float*)d_in[16];
    const float* bosa = (const float*)d_in[17];
    const float* Wval = (const float*)d_in[18];
    const float* bval = (const float*)d_in[19];
    const float* Woff = (const float*)d_in[20];
    const float* boff = (const float*)d_in[21];
    const float* Waw = (const float*)d_in[22];
    const float* baw = (const float*)d_in[23];
    const float* Woca = (const float*)d_in[24];
    const float* boca = (const float*)d_in[25];
    const float* W1 = (const float*)d_in[26];
    const float* b1f = (const float*)d_in[27];
    const float* W2 = (const float*)d_in[28];
    const float* b2f = (const float*)d_in[29];
    float* x = (float*)d_out;

    float* ws = (float*)d_ws;
    float* cpe = ws;                               // 524288
    float* offaw = cpe + 524288;                   // 1327104
    float* bval2 = offaw + 1327104;                // 512
    unsigned short* hqkv16 = (unsigned short*)(bval2 + 512);   // 1572864 shorts
    unsigned short* lnout16 = hqkv16 + 1572864;    // 524288 shorts
    unsigned short* attn16 = lnout16 + 524288;     // 524288 shorts
    unsigned short* cab16 = attn16 + 524288;       // 524288 shorts
    unsigned short* ffmid16 = cab16 + 524288;      // 1048576 shorts
    unsigned short* srcn16 = ffmid16 + 1048576;    // 11010048 shorts
    unsigned short* value16 = srcn16 + 11010048;   // 22020096 shorts
    int* kidx16 = (int*)(value16 + 22020096);      // 32768
    int* kidx64 = kidx16 + 32768;                  // 131072
    unsigned short* wt = (unsigned short*)(kidx64 + 131072);  // 2*755712 + 131072 shorts

    const size_t WT_STRIDE = 755712;
    const size_t O_WQKV = 0, O_WOSA = 196608, O_WOFFAW = 262144, O_WOCA = 428032,
                 O_W1 = 493568, O_W2 = 624640;
    unsigned short* wtval = wt + 2 * WT_STRIDE;  // [512][256]: rows 0-255 depth0, 256-511 depth1

    TJobs tj;
    for (int d = 0; d < 2; d++) {
        unsigned short* wd = wt + (size_t)d * WT_STRIDE;
        int tb = d * 9;
        tj.src[tb + 0] = Wq + (size_t)d * 65536;    tj.gam[tb + 0] = nullptr;      tj.dst[tb + 0] = wd + O_WQKV;            tj.K[tb + 0] = 256; tj.N[tb + 0] = 256;
        tj.src[tb + 1] = Wkv + (size_t)d * 131072;  tj.gam[tb + 1] = nullptr;      tj.dst[tb + 1] = wd + O_WQKV + 65536;    tj.K[tb + 1] = 256; tj.N[tb + 1] = 512;
        tj.src[tb + 2] = Wosa + (size_t)d * 65536;  tj.gam[tb + 2] = nullptr;      tj.dst[tb + 2] = wd + O_WOSA;            tj.K[tb + 2] = 256; tj.N[tb + 2] = 256;
        tj.src[tb + 3] = Woff + (size_t)d * 110592; tj.gam[tb + 3] = nullptr;      tj.dst[tb + 3] = wd + O_WOFFAW;          tj.K[tb + 3] = 256; tj.N[tb + 3] = 432;
        tj.src[tb + 4] = Waw + (size_t)d * 55296;   tj.gam[tb + 4] = nullptr;      tj.dst[tb + 4] = wd + O_WOFFAW + 110592; tj.K[tb + 4] = 256; tj.N[tb + 4] = 216;
        tj.src[tb + 5] = Woca + (size_t)d * 65536;  tj.gam[tb + 5] = nullptr;      tj.dst[tb + 5] = wd + O_WOCA;            tj.K[tb + 5] = 256; tj.N[tb + 5] = 256;
        tj.src[tb + 6] = W1 + (size_t)d * 131072;   tj.gam[tb + 6] = nullptr;      tj.dst[tb + 6] = wd + O_W1;              tj.K[tb + 6] = 256; tj.N[tb + 6] = 512;
        tj.src[tb + 7] = W2 + (size_t)d * 131072;   tj.gam[tb + 7] = nullptr;      tj.dst[tb + 7] = wd + O_W2;              tj.K[tb + 7] = 512; tj.N[tb + 7] = 256;
        tj.src[tb + 8] = Wval + (size_t)d * 65536;  tj.gam[tb + 8] = ln2g + d * 256; tj.dst[tb + 8] = wtval + (size_t)d * 65536; tj.K[tb + 8] = 256; tj.N[tb + 8] = 256;
    }
    // merged prologue: tw(4608) + cpe/fold(2176) + lnsrc(10752) = 17536 blocks
    k_init<<<17536, 256, 0, stream>>>(tj, cpos, Wpos, bpos, cpe, ln2b, Wval, bval, bval2, src, srcn16);
    k_knn2<<<512, 256, 0, stream>>>(pos3, kidx16, kidx64);

    // value for BOTH depths in one GEMM: srcn[43008,256](bf16) @ wtval^T -> bf16 [43008][512]
    k_mgemm<64, 128, 2, 2, true, false, false, false, true><<<dim3(4, 672), 256, 0, stream>>>(
        srcn16, wtval, bval2, nullptr, 0, nullptr, value16, 43008, 256, 512);

    for (int i = 0; i < 2; i++) {
        unsigned short* wd = wt + (size_t)i * WT_STRIDE;
        const float* xc = (i == 0) ? xin : x;
        // ---- self-attention (KNN) ----
        k_lnfused<<<512, 256, 0, stream>>>(xc, cpe, nullptr, ln1g + i * 256, ln1b + i * 256, lnout16);
        k_mgemm<64, 64, 2, 2, false, false, false, false, true><<<dim3(12, 32), 256, 0, stream>>>(
            lnout16, wd + O_WQKV, nullptr, nullptr, 0, nullptr, hqkv16, 2048, 256, 768);
        if (i == 0)
            k_attn<16><<<2048, 256, 0, stream>>>(hqkv16, kidx16, attn16);
        else
            k_attn<64><<<2048, 256, 0, stream>>>(hqkv16, kidx64, attn16);
        k_mgemm<32, 64, 2, 2, true, false, false, true, false><<<dim3(4, 64), 256, 0, stream>>>(
            attn16, wd + O_WOSA, bosa + i * 256, nullptr, 0, xc, x, 2048, 256, 256);

        // ---- ms-deform cross-attention ----
        k_lnfused<<<512, 256, 0, stream>>>(x, nullptr, cpe, ln2g + i * 256, ln2b + i * 256, lnout16);
        k_mgemm<64, 64, 2, 2, true, true, false, false, false><<<dim3(11, 32), 256, 0, stream>>>(
            lnout16, wd + O_WOFFAW, boff + i * 432, baw + i * 216, 432, nullptr, offaw, 2048, 256, 648);
        k_msdeform<<<2048, 256, 0, stream>>>(offaw, cpos, value16 + (size_t)i * 256, cab16);
        k_mgemm<32, 64, 2, 2, true, false, false, true, false><<<dim3(4, 64), 256, 0, stream>>>(
            cab16, wd + O_WOCA, boca + i * 256, nullptr, 0, x, x, 2048, 256, 256);

        // ---- FFN ----
        k_lnfused<<<512, 256, 0, stream>>>(x, nullptr, nullptr, ln3g + i * 256, ln3b + i * 256, lnout16);
        k_mgemm<64, 64, 2, 2, true, false, true, false, true><<<dim3(8, 32), 256, 0, stream>>>(
            lnout16, wd + O_W1, b1f + i * 512, nullptr, 0, nullptr, ffmid16, 2048, 256, 512);
        k_mgemm<32, 64, 2, 2, true, false, false, true, false><<<dim3(4, 64), 256, 0, stream>>>(
            ffmid16, wd + O_W2, b2f + i * 256, nullptr, 0, x, x, 2048, 512, 256);
    }
}